// Round 13
// baseline (163.922 us; speedup 1.0000x reference)
//
#include <hip/hip_runtime.h>

#define NNODES 50000
#define NEDGES 800000
#define IN_C   512
#define HID_C  128
#define OUT_C  64

typedef float  f32x4  __attribute__((ext_vector_type(4)));
typedef __bf16 bf16x8 __attribute__((ext_vector_type(8)));
typedef short  short8 __attribute__((ext_vector_type(8)));

#define GLDS(src, dst) \
  __builtin_amdgcn_global_load_lds( \
      (const __attribute__((address_space(1))) unsigned int*)(src), \
      (__attribute__((address_space(3))) unsigned int*)(dst), 16, 0, 0)

__device__ __forceinline__ float bf2f(unsigned short u) {
  unsigned int x = (unsigned int)u << 16;
  return __builtin_bit_cast(float, x);
}

// ---------------- prep0: clear packed + split/transpose W1,W2 (fused) ----------------
// packed: deg+count in ONE u64/node (bits[0:20)=count, [20:64)=deg*2^24), 1 per 32B sector.

__device__ __forceinline__ void wsplit_one(const float* __restrict__ W,
                                           unsigned short* __restrict__ Th,
                                           unsigned short* __restrict__ Tl,
                                           int K, int N, int id) {
  int k = id % K, n = id / K;           // consecutive id -> consecutive k (coalesced writes)
  float f = W[(size_t)k * N + n];
  __bf16 hb = (__bf16)f;
  __bf16 lb = (__bf16)(f - (float)hb);
  Th[id] = __builtin_bit_cast(unsigned short, hb);
  Tl[id] = __builtin_bit_cast(unsigned short, lb);
}

__global__ void __launch_bounds__(256) prep0_kernel(
    int4* __restrict__ packed4, int nclear4,
    const float* __restrict__ W1, unsigned short* __restrict__ W1th,
    unsigned short* __restrict__ W1tl,
    const float* __restrict__ W2, unsigned short* __restrict__ W2th,
    unsigned short* __restrict__ W2tl) {
  int id = blockIdx.x * blockDim.x + threadIdx.x;
  if (id < nclear4) { packed4[id] = make_int4(0, 0, 0, 0); return; }
  int s = id - nclear4;
  if (s < IN_C * HID_C) wsplit_one(W1, W1th, W1tl, IN_C, HID_C, s);
  else if (s < IN_C * HID_C + HID_C * OUT_C)
    wsplit_one(W2, W2th, W2tl, HID_C, OUT_C, s - IN_C * HID_C);
}

// ---------------- deg_count: STANDALONE (round-12 lesson: never co-schedule this
// atomic flood with the latency-sensitive GEMM pipeline) ----------------
__global__ void deg_count_kernel(const int* __restrict__ ei, const float* __restrict__ ew,
                                 unsigned long long* __restrict__ packed,
                                 unsigned short* __restrict__ rank, int nE) {
  int e = blockIdx.x * blockDim.x + threadIdx.x;
  if (e < nE) {
    int c = ei[nE + e];               // destination
    unsigned int fx = __float2uint_rn(ew[e] * 16777216.0f);   // ew in [0,1)
    unsigned long long old =
        atomicAdd(&packed[(size_t)c * 4], ((unsigned long long)fx << 20) | 1ULL);
    rank[e] = (unsigned short)(old & 0xFFFFFULL);   // edges-before-me at this dest
  }
}

// ---------------- f32-A split-bf16 MFMA GEMM (layer 1) ----------------
// Y[M,N] = X[M,K] @ W[K,N] -> bf16 (RNE);  Y ~= Xh@Wh + Xl@Wh + Xh@Wl
// Per K-chunk (BK=32): A f32 + B=W^T hi/lo bf16 staged via global_load_lds, dbuf,
// one barrier per chunk. Source-swizzled / read-unswizzled (rule #21).
template <int K, int N, int WR, int WC>
__global__ void __launch_bounds__(WR * WC * 64, 4) gemm_mfma_kernel(
    const float* __restrict__ X, const unsigned short* __restrict__ Bth,
    const unsigned short* __restrict__ Btl, unsigned short* __restrict__ Y, int M) {
  constexpr int NW = WR * WC;
  constexpr int BM = WR * 32;
  constexpr int NI = K / 32;
  constexpr int ASLOTS = (BM / 8) / NW;
  constexpr int BSLOTS = (N / 8) / NW;

  __shared__ float          As[2][BM * 32];
  __shared__ unsigned short Bs[2][2][N * 32];

  int tid = threadIdx.x;
  int lane = tid & 63, wid = tid >> 6;
  int wr = wid / WC, wc = wid % WC;
  int row0blk = blockIdx.x * BM;
  int row0 = row0blk + wr * 32;
  int rlo = lane & 15;
  int khi = lane >> 4;

  f32x4 acc[2][4] = {};

  auto stage = [&](int t, int buf) {
    int kb = t * 32;
#pragma unroll
    for (int i = 0; i < ASLOTS; ++i) {
      int slot = wid * ASLOTS + i;
      int rt = slot * 8 + (lane >> 3);
      int gr = row0blk + rt; gr = gr < M ? gr : M - 1;
      int gs = (lane & 7) ^ (lane >> 3);
      GLDS(X + (size_t)gr * K + kb + gs * 4, &As[buf][slot * 256]);
    }
#pragma unroll
    for (int i = 0; i < BSLOTS; ++i) {
      int slot = wid * BSLOTS + i;
      int half = slot / (N / 16);
      int idx = slot % (N / 16);
      const unsigned short* Wt = half ? Btl : Bth;
      int c = idx * 16 + (lane >> 2);
      int gs = (lane & 3) ^ (lane >> 4);
      GLDS(Wt + (size_t)c * K + kb + gs * 8, &Bs[buf][half][idx * 512]);
    }
  };

  stage(0, 0);
  __syncthreads();

#pragma unroll 1
  for (int t = 0; t < NI; ++t) {
    int buf = t & 1;
    if (t + 1 < NI) stage(t + 1, buf ^ 1);

    bf16x8 ah[2], al[2];
#pragma unroll
    for (int m = 0; m < 2; ++m) {
      int rt = wr * 32 + m * 16 + rlo;
      int p0 = (khi * 2) ^ (rlo & 7), p1 = (khi * 2 + 1) ^ (rlo & 7);
      f32x4 v0 = *reinterpret_cast<const f32x4*>(&As[buf][rt * 32 + p0 * 4]);
      f32x4 v1 = *reinterpret_cast<const f32x4*>(&As[buf][rt * 32 + p1 * 4]);
      float f[8] = {v0.x, v0.y, v0.z, v0.w, v1.x, v1.y, v1.z, v1.w};
#pragma unroll
      for (int i = 0; i < 8; ++i) {
        __bf16 hv = (__bf16)f[i];
        ah[m][i] = hv;
        al[m][i] = (__bf16)(f[i] - (float)hv);
      }
    }
    short8 bh[4], bl[4];
#pragma unroll
    for (int n = 0; n < 4; ++n) {
      int c = wc * 64 + n * 16 + rlo;
      int pos = khi ^ (rlo >> 2);
      bh[n] = *reinterpret_cast<const short8*>(&Bs[buf][0][c * 32 + pos * 8]);
      bl[n] = *reinterpret_cast<const short8*>(&Bs[buf][1][c * 32 + pos * 8]);
    }
#pragma unroll
    for (int m = 0; m < 2; ++m)
#pragma unroll
      for (int n = 0; n < 4; ++n)
        acc[m][n] = __builtin_amdgcn_mfma_f32_16x16x32_bf16(
            ah[m], __builtin_bit_cast(bf16x8, bh[n]), acc[m][n], 0, 0, 0);
#pragma unroll
    for (int m = 0; m < 2; ++m)
#pragma unroll
      for (int n = 0; n < 4; ++n)
        acc[m][n] = __builtin_amdgcn_mfma_f32_16x16x32_bf16(
            al[m], __builtin_bit_cast(bf16x8, bh[n]), acc[m][n], 0, 0, 0);
#pragma unroll
    for (int m = 0; m < 2; ++m)
#pragma unroll
      for (int n = 0; n < 4; ++n)
        acc[m][n] = __builtin_amdgcn_mfma_f32_16x16x32_bf16(
            ah[m], __builtin_bit_cast(bf16x8, bl[n]), acc[m][n], 0, 0, 0);
    __syncthreads();
  }

  // C/D: col = lane&15, row = (lane>>4)*4 + reg; store bf16 (RNE)
#pragma unroll
  for (int m = 0; m < 2; ++m)
#pragma unroll
    for (int j = 0; j < 4; ++j) {
      int row = row0 + m * 16 + khi * 4 + j;
      if (row < M) {
#pragma unroll
        for (int n = 0; n < 4; ++n) {
          __bf16 q = (__bf16)acc[m][n][j];
          Y[(size_t)row * N + wc * 64 + n * 16 + rlo] = __builtin_bit_cast(unsigned short, q);
        }
      }
    }
}

// ---------------- bf16-A MFMA GEMM (layer 2): A already bf16 -> 2 MFMA terms ----------------
// Y ~= A@Wh + A@Wl. A tile row = 64B = 4 granules; source granule ^= (lane>>3)&3
// (reads at granule khi^((rt>>1)&3) -> 8 bank-quads / 16 lanes = 2-way = free).
template <int K, int N, int WR, int WC>
__global__ void __launch_bounds__(WR * WC * 64, 4) gemm_bf16a_kernel(
    const unsigned short* __restrict__ X, const unsigned short* __restrict__ Bth,
    const unsigned short* __restrict__ Btl, unsigned short* __restrict__ Y, int M) {
  constexpr int NW = WR * WC;
  constexpr int BM = WR * 32;
  constexpr int NI = K / 32;
  constexpr int ASLOTS = (BM / 16) / NW;   // 1KB slot = 16 rows x 64B
  constexpr int BSLOTS = (N / 8) / NW;

  __shared__ unsigned short As[2][BM * 32];
  __shared__ unsigned short Bs[2][2][N * 32];

  int tid = threadIdx.x;
  int lane = tid & 63, wid = tid >> 6;
  int wr = wid / WC, wc = wid % WC;
  int row0blk = blockIdx.x * BM;
  int row0 = row0blk + wr * 32;
  int rlo = lane & 15;
  int khi = lane >> 4;

  f32x4 acc[2][4] = {};

  auto stage = [&](int t, int buf) {
    int kb = t * 32;
#pragma unroll
    for (int i = 0; i < ASLOTS; ++i) {
      int slot = wid * ASLOTS + i;
      int rt = slot * 16 + (lane >> 2);
      int gr = row0blk + rt; gr = gr < M ? gr : M - 1;
      int gs = (lane & 3) ^ ((lane >> 3) & 3);
      GLDS(X + (size_t)gr * K + kb + gs * 8, &As[buf][slot * 512]);
    }
#pragma unroll
    for (int i = 0; i < BSLOTS; ++i) {
      int slot = wid * BSLOTS + i;
      int half = slot / (N / 16);
      int idx = slot % (N / 16);
      const unsigned short* Wt = half ? Btl : Bth;
      int c = idx * 16 + (lane >> 2);
      int gs = (lane & 3) ^ (lane >> 4);
      GLDS(Wt + (size_t)c * K + kb + gs * 8, &Bs[buf][half][idx * 512]);
    }
  };

  stage(0, 0);
  __syncthreads();

#pragma unroll 1
  for (int t = 0; t < NI; ++t) {
    int buf = t & 1;
    if (t + 1 < NI) stage(t + 1, buf ^ 1);

    short8 ah[2];
#pragma unroll
    for (int m = 0; m < 2; ++m) {
      int rt = wr * 32 + m * 16 + rlo;
      int g = khi ^ ((rt >> 1) & 3);
      ah[m] = *reinterpret_cast<const short8*>(&As[buf][rt * 32 + g * 8]);
    }
    short8 bh[4], bl[4];
#pragma unroll
    for (int n = 0; n < 4; ++n) {
      int c = wc * 64 + n * 16 + rlo;
      int pos = khi ^ (rlo >> 2);
      bh[n] = *reinterpret_cast<const short8*>(&Bs[buf][0][c * 32 + pos * 8]);
      bl[n] = *reinterpret_cast<const short8*>(&Bs[buf][1][c * 32 + pos * 8]);
    }
#pragma unroll
    for (int m = 0; m < 2; ++m)
#pragma unroll
      for (int n = 0; n < 4; ++n)
        acc[m][n] = __builtin_amdgcn_mfma_f32_16x16x32_bf16(
            __builtin_bit_cast(bf16x8, ah[m]), __builtin_bit_cast(bf16x8, bh[n]),
            acc[m][n], 0, 0, 0);
#pragma unroll
    for (int m = 0; m < 2; ++m)
#pragma unroll
      for (int n = 0; n < 4; ++n)
        acc[m][n] = __builtin_amdgcn_mfma_f32_16x16x32_bf16(
            __builtin_bit_cast(bf16x8, ah[m]), __builtin_bit_cast(bf16x8, bl[n]),
            acc[m][n], 0, 0, 0);
    __syncthreads();
  }

#pragma unroll
  for (int m = 0; m < 2; ++m)
#pragma unroll
    for (int j = 0; j < 4; ++j) {
      int row = row0 + m * 16 + khi * 4 + j;
      if (row < M) {
#pragma unroll
        for (int n = 0; n < 4; ++n) {
          __bf16 q = (__bf16)acc[m][n][j];
          Y[(size_t)row * N + wc * 64 + n * 16 + rlo] = __builtin_bit_cast(unsigned short, q);
        }
      }
    }
}

// ---------------- decode + scan_partial (fused) ----------------

__global__ void __launch_bounds__(256) decode_scan_kernel(
    const unsigned long long* __restrict__ packed, float* __restrict__ dinv,
    int* __restrict__ counts, int* __restrict__ bsum, int n) {
  int t = threadIdx.x;
  int i0 = blockIdx.x * 1024 + t * 4;
  int s = 0;
#pragma unroll
  for (int j = 0; j < 4; ++j) {
    int i = i0 + j;
    if (i < n) {
      unsigned long long p = packed[(size_t)i * 4];
      int cnt = (int)(p & 0xFFFFFULL) + 1;
      counts[i] = cnt;
      float deg = (float)((double)(p >> 20) * (1.0 / 16777216.0) + 1.0);
      dinv[i] = rsqrtf(deg);
      s += cnt;
    }
  }
#pragma unroll
  for (int off = 32; off; off >>= 1) s += __shfl_down(s, off);
  __shared__ int ws[4];
  if ((t & 63) == 0) ws[t >> 6] = s;
  __syncthreads();
  if (t == 0) bsum[blockIdx.x] = ws[0] + ws[1] + ws[2] + ws[3];
}

__global__ void scan_bsum_kernel(int* __restrict__ bsum, int nb) {
  int lane = threadIdx.x;
  int orig = lane < nb ? bsum[lane] : 0;
  int v = orig;
#pragma unroll
  for (int off = 1; off < 64; off <<= 1) {
    int u = __shfl_up(v, off);
    if (lane >= off) v += u;
  }
  if (lane < nb) bsum[lane] = v - orig;   // exclusive
}

__global__ void __launch_bounds__(256) scan_final_kernel(const int* __restrict__ counts,
                                                         const int* __restrict__ bscan,
                                                         int* __restrict__ offs, int n) {
  int t = threadIdx.x;
  int lane = t & 63, wid = t >> 6;
  int b = blockIdx.x;
  int i0 = b * 1024 + t * 4;
  int c[4];
#pragma unroll
  for (int j = 0; j < 4; ++j) c[j] = (i0 + j < n) ? counts[i0 + j] : 0;
  int s = c[0] + c[1] + c[2] + c[3];
  int v = s;
#pragma unroll
  for (int off = 1; off < 64; off <<= 1) {
    int u = __shfl_up(v, off);
    if (lane >= off) v += u;
  }
  __shared__ int wtot[4];
  if (lane == 63) wtot[wid] = v;
  __syncthreads();
  int wpre = 0;
#pragma unroll
  for (int w = 0; w < 4; ++w) if (w < wid) wpre += wtot[w];
  int p = bscan[b] + wpre + (v - s);
#pragma unroll
  for (int j = 0; j < 4; ++j) {
    if (i0 + j < n) offs[i0 + j] = p;
    p += c[j];
  }
  if (b == gridDim.x - 1 && t == 255)
    offs[n] = bscan[b] + wtot[0] + wtot[1] + wtot[2] + wtot[3];
}

// fill CSR, ATOMIC-FREE: pos = offs[c] + 1 + rank[e]; record u32 (row:16 | f16 norm:16)
__global__ void fill_kernel(const int* __restrict__ ei, const float* __restrict__ ew,
                            const float* __restrict__ dinv, const int* __restrict__ offs,
                            const unsigned short* __restrict__ rank,
                            unsigned int* __restrict__ edges, int nE, int nN) {
  int i = blockIdx.x * blockDim.x + threadIdx.x;
  if (i < nN) {
    float di = dinv[i];
    _Float16 hf = (_Float16)(di * di);
    unsigned int rec = (unsigned int)i |
                       ((unsigned int)__builtin_bit_cast(unsigned short, hf) << 16);
    __builtin_nontemporal_store(rec, &edges[offs[i]]);
  } else if (i < nN + nE) {
    int e = i - nN;
    int r = ei[e], c = ei[nE + e];
    float w = dinv[r] * ew[e] * dinv[c];
    _Float16 hf = (_Float16)w;
    int pos = offs[c] + 1 + (int)rank[e];
    unsigned int rec = (unsigned int)r |
                       ((unsigned int)__builtin_bit_cast(unsigned short, hf) << 16);
    __builtin_nontemporal_store(rec, &edges[pos]);
  }
}

// ---------------- CSR aggregation over bf16 features ----------------
// acc f32; output f32 (final layer) or bf16 (hidden layer, halves write+reread traffic)
template <int F, bool RELU, bool OUTBF>
__global__ void __launch_bounds__(256) agg_kernel(const unsigned short* __restrict__ feat,
                                                  const int* __restrict__ offs,
                                                  const unsigned int* __restrict__ edges,
                                                  const float* __restrict__ bias,
                                                  void* __restrict__ outv, int n) {
  constexpr int LPN = F / 8;
  constexpr int NPW = 64 / LPN;
  constexpr int NPB = 4 * NPW;
  int wid = threadIdx.x >> 6;
  int lane = threadIdx.x & 63;
  int node = blockIdx.x * NPB + wid * NPW + lane / LPN;
  int lf = (lane % LPN) * 8;
  if (node >= n) return;
  int e0 = offs[node], e1 = offs[node + 1];

  float acc[8];
#pragma unroll
  for (int j = 0; j < 8; ++j) acc[j] = bias[lf + j];

  auto fmaEdge = [&](unsigned int q) {
    float w = (float)__builtin_bit_cast(_Float16, (unsigned short)(q >> 16));
    int row = (int)(q & 0xFFFFu);
    short8 v = *reinterpret_cast<const short8*>(&feat[(size_t)row * F + lf]);
#pragma unroll
    for (int j = 0; j < 8; ++j)
      acc[j] = fmaf(w, bf2f((unsigned short)v[j]), acc[j]);
  };

  int e = e0;
  for (; e + 4 <= e1; e += 4) {
    unsigned int q0 = edges[e], q1 = edges[e + 1], q2 = edges[e + 2], q3 = edges[e + 3];
    fmaEdge(q0); fmaEdge(q1); fmaEdge(q2); fmaEdge(q3);
  }
  for (; e < e1; ++e) fmaEdge(edges[e]);

  if (RELU) {
#pragma unroll
    for (int j = 0; j < 8; ++j) acc[j] = fmaxf(acc[j], 0.f);
  }
  if constexpr (OUTBF) {
    short8 o;
#pragma unroll
    for (int j = 0; j < 8; ++j) {
      __bf16 q = (__bf16)acc[j];
      o[j] = (short)__builtin_bit_cast(unsigned short, q);
    }
    *reinterpret_cast<short8*>((unsigned short*)outv + (size_t)node * F + lf) = o;
  } else {
    float* out = (float*)outv;
    float4 o0 = make_float4(acc[0], acc[1], acc[2], acc[3]);
    float4 o1 = make_float4(acc[4], acc[5], acc[6], acc[7]);
    *reinterpret_cast<float4*>(&out[(size_t)node * F + lf]) = o0;
    *reinterpret_cast<float4*>(&out[(size_t)node * F + lf + 4]) = o1;
  }
}

// ---------------- launch ----------------

extern "C" void kernel_launch(void* const* d_in, const int* in_sizes, int n_in,
                              void* d_out, int out_size, void* d_ws, size_t ws_size,
                              hipStream_t stream) {
  const float* x  = (const float*)d_in[0];
  const int*   ei = (const int*)d_in[1];     // [2, E] int
  const float* ew = (const float*)d_in[2];
  const float* W1 = (const float*)d_in[3];
  const float* b1 = (const float*)d_in[4];
  const float* W2 = (const float*)d_in[5];
  const float* b2 = (const float*)d_in[6];
  float* out = (float*)d_out;

  const int N = NNODES, E = NEDGES, EP = NNODES + NEDGES;
  const int NB = (N + 1023) / 1024;          // scan blocks (49)

  char* p = (char*)d_ws;
  auto alloc = [&](size_t bytes) { char* r = p; p += (bytes + 255) & ~(size_t)255; return r; };
  unsigned long long* packed = (unsigned long long*)alloc((size_t)N * 32);
  float* dinv   = (float*)alloc((size_t)N * 4);
  int*   counts = (int*)  alloc((size_t)N * 4);
  int*   offs   = (int*)  alloc((size_t)(N + 1) * 4);
  int*   bsum   = (int*)  alloc((size_t)64 * 4);
  unsigned short* rank = (unsigned short*)alloc((size_t)E * 2);
  unsigned int* edges  = (unsigned int*)alloc((size_t)EP * 4);
  unsigned short* xw = (unsigned short*)alloc((size_t)N * HID_C * 2); // bf16 pre-agg / h2
  unsigned short* h  = (unsigned short*)alloc((size_t)N * HID_C * 2); // bf16 layer-1 out
  unsigned short* W1th = (unsigned short*)alloc((size_t)IN_C * HID_C * 2);
  unsigned short* W1tl = (unsigned short*)alloc((size_t)IN_C * HID_C * 2);
  unsigned short* W2th = (unsigned short*)alloc((size_t)HID_C * OUT_C * 2);
  unsigned short* W2tl = (unsigned short*)alloc((size_t)HID_C * OUT_C * 2);

  // prep0: clear packed (100000 int4) + wsplit W1,W2
  const int NCLEAR4 = N * 32 / 16;
  const int PREP0 = NCLEAR4 + IN_C * HID_C + HID_C * OUT_C;
  prep0_kernel<<<(PREP0 + 255) / 256, 256, 0, stream>>>(
      (int4*)packed, NCLEAR4, W1, W1th, W1tl, W2, W2th, W2tl);

  deg_count_kernel<<<(E + 255) / 256, 256, 0, stream>>>(ei, ew, packed, rank, E);

  // layer 1 GEMM: xw = bf16(x @ W1)   [BM=128, N=128, 8 waves]
  gemm_mfma_kernel<IN_C, HID_C, 4, 2><<<(N + 127) / 128, 512, 0, stream>>>(x, W1th, W1tl, xw, N);

  decode_scan_kernel<<<NB, 256, 0, stream>>>(packed, dinv, counts, bsum, N);
  scan_bsum_kernel<<<1, 64, 0, stream>>>(bsum, NB);
  scan_final_kernel<<<NB, 256, 0, stream>>>(counts, bsum, offs, N);
  fill_kernel<<<(EP + 255) / 256, 256, 0, stream>>>(ei, ew, dinv, offs, rank, edges, E, N);

  // layer 1 agg: h = bf16(relu(agg(xw) + b1))
  agg_kernel<HID_C, true, true><<<(N + 15) / 16, 256, 0, stream>>>(xw, offs, edges, b1, h, N);

  // layer 2: h2 = bf16(h @ W2)  [bf16-A GEMM, BM=256, N=64, 8 waves]
  gemm_bf16a_kernel<HID_C, OUT_C, 8, 1><<<(N + 255) / 256, 512, 0, stream>>>(h, W2th, W2tl, xw, N);
  agg_kernel<OUT_C, false, false><<<(N + 31) / 32, 256, 0, stream>>>(xw, offs, edges, b2, out, N);
}

// Round 14
// 124.740 us; speedup vs baseline: 1.3141x; 1.3141x over previous
//
#include <hip/hip_runtime.h>

#define NNODES 50000
#define NEDGES 800000
#define IN_C   512
#define HID_C  128
#define OUT_C  64
#define NBUCK  196        // ceil(50000/256); bucket = dest >> 8
#define IMGCAP 8192       // LDS CSR image capacity (bucket max ~4400 edges + 256)

typedef float  f32x4  __attribute__((ext_vector_type(4)));
typedef __bf16 bf16x8 __attribute__((ext_vector_type(8)));
typedef short  short8 __attribute__((ext_vector_type(8)));

#define GLDS(src, dst) \
  __builtin_amdgcn_global_load_lds( \
      (const __attribute__((address_space(1))) unsigned int*)(src), \
      (__attribute__((address_space(3))) unsigned int*)(dst), 16, 0, 0)

__device__ __forceinline__ float bf2f(unsigned short u) {
  unsigned int x = (unsigned int)u << 16;
  return __builtin_bit_cast(float, x);
}
__device__ __forceinline__ unsigned short f16bits(float f) {
  _Float16 h = (_Float16)f;
  return __builtin_bit_cast(unsigned short, h);
}
__device__ __forceinline__ float f16val(unsigned short u) {
  return (float)__builtin_bit_cast(_Float16, u);
}

// ---------------- prep0: zero bin counters + split/transpose W1,W2 ----------------

__device__ __forceinline__ void wsplit_one(const float* __restrict__ W,
                                           unsigned short* __restrict__ Th,
                                           unsigned short* __restrict__ Tl,
                                           int K, int N, int id) {
  int k = id % K, n = id / K;           // consecutive id -> consecutive k (coalesced writes)
  float f = W[(size_t)k * N + n];
  __bf16 hb = (__bf16)f;
  __bf16 lb = (__bf16)(f - (float)hb);
  Th[id] = __builtin_bit_cast(unsigned short, hb);
  Tl[id] = __builtin_bit_cast(unsigned short, lb);
}

__global__ void __launch_bounds__(256) prep0_kernel(
    unsigned int* __restrict__ gbin,
    const float* __restrict__ W1, unsigned short* __restrict__ W1th,
    unsigned short* __restrict__ W1tl,
    const float* __restrict__ W2, unsigned short* __restrict__ W2th,
    unsigned short* __restrict__ W2tl) {
  int id = blockIdx.x * blockDim.x + threadIdx.x;
  if (id < 256) { if (id <= NBUCK) gbin[id] = 0; return; }
  int s = id - 256;
  if (s < IN_C * HID_C) wsplit_one(W1, W1th, W1tl, IN_C, HID_C, s);
  else if (s < IN_C * HID_C + HID_C * OUT_C)
    wsplit_one(W2, W2th, W2tl, HID_C, OUT_C, s - IN_C * HID_C);
}

// ---------------- B1: per-bucket edge histogram (LDS-aggregated) ----------------
// 1024 thr x 8 edges = 8192/block; 196 global atomics per block (trivial contention)

__global__ void __launch_bounds__(1024) bin_hist_kernel(const int* __restrict__ ei,
                                                        unsigned int* __restrict__ gbin,
                                                        int nE) {
  __shared__ unsigned int h[NBUCK];
  int t = threadIdx.x;
  if (t < NBUCK) h[t] = 0;
  __syncthreads();
  int base = blockIdx.x * 8192;
#pragma unroll
  for (int i = 0; i < 8; ++i) {
    int e = base + i * 1024 + t;
    if (e < nE) atomicAdd(&h[((unsigned int)ei[nE + e]) >> 8], 1u);
  }
  __syncthreads();
  if (t < NBUCK && h[t]) atomicAdd(&gbin[t], h[t]);
}

// ---------------- B2: scan 196 bucket totals -> binoff + claim cursors ----------------

__global__ void __launch_bounds__(256) bin_scan_kernel(const unsigned int* __restrict__ gbin,
                                                       unsigned int* __restrict__ binoff,
                                                       unsigned int* __restrict__ gclaim) {
  int t = threadIdx.x;
  unsigned int v = (t < NBUCK) ? gbin[t] : 0;
  __shared__ unsigned int s[256];
  s[t] = v;
  __syncthreads();
  for (int off = 1; off < 256; off <<= 1) {
    unsigned int u = (t >= off) ? s[t - off] : 0;
    __syncthreads();
    s[t] += u;
    __syncthreads();
  }
  unsigned int excl = s[t] - v;
  if (t < NBUCK) { binoff[t] = excl; gclaim[t] = excl; }
  if (t == 255) binoff[NBUCK] = s[255];   // = E
}

// ---------------- B3: scatter edges into bucket-ordered array ----------------
// per-block LDS histogram -> ONE returning atomic per (block,bin) claims a range ->
// per-bin consecutive writes (near-full sectors). Record u64: src:16 | dest_lo:8 | f16(ew):16.

__global__ void __launch_bounds__(1024) bin_scatter_kernel(
    const int* __restrict__ ei, const float* __restrict__ ew,
    unsigned int* __restrict__ gclaim, unsigned long long* __restrict__ binned, int nE) {
  __shared__ unsigned int h[NBUCK];
  __shared__ unsigned int cur[NBUCK];
  int t = threadIdx.x;
  if (t < NBUCK) h[t] = 0;
  __syncthreads();
  int base = blockIdx.x * 8192;
  int r[8]; unsigned int c[8]; unsigned short wb[8];
#pragma unroll
  for (int i = 0; i < 8; ++i) {
    int e = base + i * 1024 + t;
    if (e < nE) {
      r[i] = ei[e];
      c[i] = (unsigned int)ei[nE + e];
      wb[i] = f16bits(ew[e]);
      atomicAdd(&h[c[i] >> 8], 1u);
    } else {
      c[i] = 0xFFFFFFFFu;
    }
  }
  __syncthreads();
  if (t < NBUCK) cur[t] = h[t] ? atomicAdd(&gclaim[t], h[t]) : 0u;
  __syncthreads();
#pragma unroll
  for (int i = 0; i < 8; ++i) {
    if (c[i] != 0xFFFFFFFFu) {
      unsigned int pos = atomicAdd(&cur[c[i] >> 8], 1u);
      unsigned long long rec = (unsigned long long)((unsigned int)r[i] & 0xFFFFu)
                             | ((unsigned long long)(c[i] & 0xFFu) << 16)
                             | ((unsigned long long)wb[i] << 32);
      binned[pos] = rec;
    }
  }
}

// ---------------- B4a: per-bucket deg/dinv/offs (LDS integer atomics, deterministic) ----

__global__ void __launch_bounds__(256) bucket_deg_kernel(
    const unsigned long long* __restrict__ binned, const unsigned int* __restrict__ binoff,
    float* __restrict__ dinv, int* __restrict__ offs) {
  int b = blockIdx.x, t = threadIdx.x;
  int base = (int)binoff[b];
  int cnt = (int)binoff[b + 1] - base;
  int nb = min(256, NNODES - b * 256);
  __shared__ unsigned int ec[256], wf[256];
  __shared__ int sc[256];
  ec[t] = 0; wf[t] = 0;
  __syncthreads();
  for (int i = t; i < cnt; i += 256) {
    unsigned long long rec = binned[base + i];
    int dlo = (int)((rec >> 16) & 255ULL);
    atomicAdd(&ec[dlo], 1u);
    float w = f16val((unsigned short)(rec >> 32));
    atomicAdd(&wf[dlo], (unsigned int)(w * 1048576.0f + 0.5f));   // fixed-point 2^20
  }
  __syncthreads();
  int cn = (t < nb) ? (int)ec[t] + 1 : 0;   // + self-loop slot
  sc[t] = cn;
  __syncthreads();
  for (int off = 1; off < 256; off <<= 1) {
    int u = (t >= off) ? sc[t - off] : 0;
    __syncthreads();
    sc[t] += u;
    __syncthreads();
  }
  if (t < nb) {
    float deg = (float)wf[t] * (1.0f / 1048576.0f) + 1.0f;   // + self-loop w=1
    int g = b * 256 + t;
    int csrbase = base + b * 256;
    dinv[g] = rsqrtf(deg);
    offs[g] = csrbase + sc[t] - cn;
    if (b == NBUCK - 1 && t == nb - 1) offs[NNODES] = csrbase + sc[t];
  }
}

// ---------------- B4b: per-bucket normalize + CSR build in LDS + coalesced out ----------
// final record u32: src:16 | f16(dinv[src]*ew*dinv[dest]):16

__global__ void __launch_bounds__(256) bucket_fill_kernel(
    const unsigned long long* __restrict__ binned, const unsigned int* __restrict__ binoff,
    const float* __restrict__ dinv, const int* __restrict__ offs,
    unsigned int* __restrict__ edges) {
  int b = blockIdx.x, t = threadIdx.x;
  int base = (int)binoff[b];
  int cnt = (int)binoff[b + 1] - base;
  int nb = min(256, NNODES - b * 256);
  int csrbase = base + b * 256;
  __shared__ unsigned int image[IMGCAP];
  __shared__ unsigned int cur[256];
  __shared__ float ldv[256];
  float di = 0.f;
  if (t < nb) {
    int g = b * 256 + t;
    di = dinv[g];
    int loc = offs[g] - csrbase;
    cur[t] = (unsigned int)(loc + 1);
    image[loc] = (unsigned int)g | ((unsigned int)f16bits(di * di) << 16);  // self-loop
  }
  ldv[t] = di;
  __syncthreads();
  for (int i = t; i < cnt; i += 256) {
    unsigned long long rec = binned[base + i];
    int src = (int)(rec & 0xFFFFULL);
    int dlo = (int)((rec >> 16) & 255ULL);
    float w = f16val((unsigned short)(rec >> 32));
    float nm = dinv[src] * w * ldv[dlo];
    unsigned int pos = atomicAdd(&cur[dlo], 1u);
    image[pos] = (unsigned int)src | ((unsigned int)f16bits(nm) << 16);
  }
  __syncthreads();
  int total = cnt + nb;
  for (int j = t; j < total; j += 256) edges[csrbase + j] = image[j];
}

// ---------------- f32-A split-bf16 MFMA GEMM (layer 1) ----------------
// Y[M,N] = X[M,K] @ W[K,N] -> bf16 (RNE);  Y ~= Xh@Wh + Xl@Wh + Xh@Wl
template <int K, int N, int WR, int WC>
__global__ void __launch_bounds__(WR * WC * 64, 4) gemm_mfma_kernel(
    const float* __restrict__ X, const unsigned short* __restrict__ Bth,
    const unsigned short* __restrict__ Btl, unsigned short* __restrict__ Y, int M) {
  constexpr int NW = WR * WC;
  constexpr int BM = WR * 32;
  constexpr int NI = K / 32;
  constexpr int ASLOTS = (BM / 8) / NW;
  constexpr int BSLOTS = (N / 8) / NW;

  __shared__ float          As[2][BM * 32];
  __shared__ unsigned short Bs[2][2][N * 32];

  int tid = threadIdx.x;
  int lane = tid & 63, wid = tid >> 6;
  int wr = wid / WC, wc = wid % WC;
  int row0blk = blockIdx.x * BM;
  int row0 = row0blk + wr * 32;
  int rlo = lane & 15;
  int khi = lane >> 4;

  f32x4 acc[2][4] = {};

  auto stage = [&](int t, int buf) {
    int kb = t * 32;
#pragma unroll
    for (int i = 0; i < ASLOTS; ++i) {
      int slot = wid * ASLOTS + i;
      int rt = slot * 8 + (lane >> 3);
      int gr = row0blk + rt; gr = gr < M ? gr : M - 1;
      int gs = (lane & 7) ^ (lane >> 3);
      GLDS(X + (size_t)gr * K + kb + gs * 4, &As[buf][slot * 256]);
    }
#pragma unroll
    for (int i = 0; i < BSLOTS; ++i) {
      int slot = wid * BSLOTS + i;
      int half = slot / (N / 16);
      int idx = slot % (N / 16);
      const unsigned short* Wt = half ? Btl : Bth;
      int c = idx * 16 + (lane >> 2);
      int gs = (lane & 3) ^ (lane >> 4);
      GLDS(Wt + (size_t)c * K + kb + gs * 8, &Bs[buf][half][idx * 512]);
    }
  };

  stage(0, 0);
  __syncthreads();

#pragma unroll 1
  for (int t = 0; t < NI; ++t) {
    int buf = t & 1;
    if (t + 1 < NI) stage(t + 1, buf ^ 1);

    bf16x8 ah[2], al[2];
#pragma unroll
    for (int m = 0; m < 2; ++m) {
      int rt = wr * 32 + m * 16 + rlo;
      int p0 = (khi * 2) ^ (rlo & 7), p1 = (khi * 2 + 1) ^ (rlo & 7);
      f32x4 v0 = *reinterpret_cast<const f32x4*>(&As[buf][rt * 32 + p0 * 4]);
      f32x4 v1 = *reinterpret_cast<const f32x4*>(&As[buf][rt * 32 + p1 * 4]);
      float f[8] = {v0.x, v0.y, v0.z, v0.w, v1.x, v1.y, v1.z, v1.w};
#pragma unroll
      for (int i = 0; i < 8; ++i) {
        __bf16 hv = (__bf16)f[i];
        ah[m][i] = hv;
        al[m][i] = (__bf16)(f[i] - (float)hv);
      }
    }
    short8 bh[4], bl[4];
#pragma unroll
    for (int n = 0; n < 4; ++n) {
      int c = wc * 64 + n * 16 + rlo;
      int pos = khi ^ (rlo >> 2);
      bh[n] = *reinterpret_cast<const short8*>(&Bs[buf][0][c * 32 + pos * 8]);
      bl[n] = *reinterpret_cast<const short8*>(&Bs[buf][1][c * 32 + pos * 8]);
    }
#pragma unroll
    for (int m = 0; m < 2; ++m)
#pragma unroll
      for (int n = 0; n < 4; ++n)
        acc[m][n] = __builtin_amdgcn_mfma_f32_16x16x32_bf16(
            ah[m], __builtin_bit_cast(bf16x8, bh[n]), acc[m][n], 0, 0, 0);
#pragma unroll
    for (int m = 0; m < 2; ++m)
#pragma unroll
      for (int n = 0; n < 4; ++n)
        acc[m][n] = __builtin_amdgcn_mfma_f32_16x16x32_bf16(
            al[m], __builtin_bit_cast(bf16x8, bh[n]), acc[m][n], 0, 0, 0);
#pragma unroll
    for (int m = 0; m < 2; ++m)
#pragma unroll
      for (int n = 0; n < 4; ++n)
        acc[m][n] = __builtin_amdgcn_mfma_f32_16x16x32_bf16(
            ah[m], __builtin_bit_cast(bf16x8, bl[n]), acc[m][n], 0, 0, 0);
    __syncthreads();
  }

  // C/D: col = lane&15, row = (lane>>4)*4 + reg; store bf16 (RNE)
#pragma unroll
  for (int m = 0; m < 2; ++m)
#pragma unroll
    for (int j = 0; j < 4; ++j) {
      int row = row0 + m * 16 + khi * 4 + j;
      if (row < M) {
#pragma unroll
        for (int n = 0; n < 4; ++n) {
          __bf16 q = (__bf16)acc[m][n][j];
          Y[(size_t)row * N + wc * 64 + n * 16 + rlo] = __builtin_bit_cast(unsigned short, q);
        }
      }
    }
}

// ---------------- bf16-A MFMA GEMM (layer 2): A already bf16 -> 2 MFMA terms ----------------
template <int K, int N, int WR, int WC>
__global__ void __launch_bounds__(WR * WC * 64, 4) gemm_bf16a_kernel(
    const unsigned short* __restrict__ X, const unsigned short* __restrict__ Bth,
    const unsigned short* __restrict__ Btl, unsigned short* __restrict__ Y, int M) {
  constexpr int NW = WR * WC;
  constexpr int BM = WR * 32;
  constexpr int NI = K / 32;
  constexpr int ASLOTS = (BM / 16) / NW;
  constexpr int BSLOTS = (N / 8) / NW;

  __shared__ unsigned short As[2][BM * 32];
  __shared__ unsigned short Bs[2][2][N * 32];

  int tid = threadIdx.x;
  int lane = tid & 63, wid = tid >> 6;
  int wr = wid / WC, wc = wid % WC;
  int row0blk = blockIdx.x * BM;
  int row0 = row0blk + wr * 32;
  int rlo = lane & 15;
  int khi = lane >> 4;

  f32x4 acc[2][4] = {};

  auto stage = [&](int t, int buf) {
    int kb = t * 32;
#pragma unroll
    for (int i = 0; i < ASLOTS; ++i) {
      int slot = wid * ASLOTS + i;
      int rt = slot * 16 + (lane >> 2);
      int gr = row0blk + rt; gr = gr < M ? gr : M - 1;
      int gs = (lane & 3) ^ ((lane >> 3) & 3);
      GLDS(X + (size_t)gr * K + kb + gs * 8, &As[buf][slot * 512]);
    }
#pragma unroll
    for (int i = 0; i < BSLOTS; ++i) {
      int slot = wid * BSLOTS + i;
      int half = slot / (N / 16);
      int idx = slot % (N / 16);
      const unsigned short* Wt = half ? Btl : Bth;
      int c = idx * 16 + (lane >> 2);
      int gs = (lane & 3) ^ (lane >> 4);
      GLDS(Wt + (size_t)c * K + kb + gs * 8, &Bs[buf][half][idx * 512]);
    }
  };

  stage(0, 0);
  __syncthreads();

#pragma unroll 1
  for (int t = 0; t < NI; ++t) {
    int buf = t & 1;
    if (t + 1 < NI) stage(t + 1, buf ^ 1);

    short8 ah[2];
#pragma unroll
    for (int m = 0; m < 2; ++m) {
      int rt = wr * 32 + m * 16 + rlo;
      int g = khi ^ ((rt >> 1) & 3);
      ah[m] = *reinterpret_cast<const short8*>(&As[buf][rt * 32 + g * 8]);
    }
    short8 bh[4], bl[4];
#pragma unroll
    for (int n = 0; n < 4; ++n) {
      int c = wc * 64 + n * 16 + rlo;
      int pos = khi ^ (rlo >> 2);
      bh[n] = *reinterpret_cast<const short8*>(&Bs[buf][0][c * 32 + pos * 8]);
      bl[n] = *reinterpret_cast<const short8*>(&Bs[buf][1][c * 32 + pos * 8]);
    }
#pragma unroll
    for (int m = 0; m < 2; ++m)
#pragma unroll
      for (int n = 0; n < 4; ++n)
        acc[m][n] = __builtin_amdgcn_mfma_f32_16x16x32_bf16(
            __builtin_bit_cast(bf16x8, ah[m]), __builtin_bit_cast(bf16x8, bh[n]),
            acc[m][n], 0, 0, 0);
#pragma unroll
    for (int m = 0; m < 2; ++m)
#pragma unroll
      for (int n = 0; n < 4; ++n)
        acc[m][n] = __builtin_amdgcn_mfma_f32_16x16x32_bf16(
            __builtin_bit_cast(bf16x8, ah[m]), __builtin_bit_cast(bf16x8, bl[n]),
            acc[m][n], 0, 0, 0);
    __syncthreads();
  }

#pragma unroll
  for (int m = 0; m < 2; ++m)
#pragma unroll
    for (int j = 0; j < 4; ++j) {
      int row = row0 + m * 16 + khi * 4 + j;
      if (row < M) {
#pragma unroll
        for (int n = 0; n < 4; ++n) {
          __bf16 q = (__bf16)acc[m][n][j];
          Y[(size_t)row * N + wc * 64 + n * 16 + rlo] = __builtin_bit_cast(unsigned short, q);
        }
      }
    }
}

// ---------------- CSR aggregation over bf16 features ----------------
template <int F, bool RELU, bool OUTBF>
__global__ void __launch_bounds__(256) agg_kernel(const unsigned short* __restrict__ feat,
                                                  const int* __restrict__ offs,
                                                  const unsigned int* __restrict__ edges,
                                                  const float* __restrict__ bias,
                                                  void* __restrict__ outv, int n) {
  constexpr int LPN = F / 8;
  constexpr int NPW = 64 / LPN;
  constexpr int NPB = 4 * NPW;
  int wid = threadIdx.x >> 6;
  int lane = threadIdx.x & 63;
  int node = blockIdx.x * NPB + wid * NPW + lane / LPN;
  int lf = (lane % LPN) * 8;
  if (node >= n) return;
  int e0 = offs[node], e1 = offs[node + 1];

  float acc[8];
#pragma unroll
  for (int j = 0; j < 8; ++j) acc[j] = bias[lf + j];

  auto fmaEdge = [&](unsigned int q) {
    float w = f16val((unsigned short)(q >> 16));
    int row = (int)(q & 0xFFFFu);
    short8 v = *reinterpret_cast<const short8*>(&feat[(size_t)row * F + lf]);
#pragma unroll
    for (int j = 0; j < 8; ++j)
      acc[j] = fmaf(w, bf2f((unsigned short)v[j]), acc[j]);
  };

  int e = e0;
  for (; e + 4 <= e1; e += 4) {
    unsigned int q0 = edges[e], q1 = edges[e + 1], q2 = edges[e + 2], q3 = edges[e + 3];
    fmaEdge(q0); fmaEdge(q1); fmaEdge(q2); fmaEdge(q3);
  }
  for (; e < e1; ++e) fmaEdge(edges[e]);

  if (RELU) {
#pragma unroll
    for (int j = 0; j < 8; ++j) acc[j] = fmaxf(acc[j], 0.f);
  }
  if constexpr (OUTBF) {
    short8 o;
#pragma unroll
    for (int j = 0; j < 8; ++j) {
      __bf16 q = (__bf16)acc[j];
      o[j] = (short)__builtin_bit_cast(unsigned short, q);
    }
    *reinterpret_cast<short8*>((unsigned short*)outv + (size_t)node * F + lf) = o;
  } else {
    float* out = (float*)outv;
    float4 o0 = make_float4(acc[0], acc[1], acc[2], acc[3]);
    float4 o1 = make_float4(acc[4], acc[5], acc[6], acc[7]);
    *reinterpret_cast<float4*>(&out[(size_t)node * F + lf]) = o0;
    *reinterpret_cast<float4*>(&out[(size_t)node * F + lf + 4]) = o1;
  }
}

// ---------------- launch ----------------

extern "C" void kernel_launch(void* const* d_in, const int* in_sizes, int n_in,
                              void* d_out, int out_size, void* d_ws, size_t ws_size,
                              hipStream_t stream) {
  const float* x  = (const float*)d_in[0];
  const int*   ei = (const int*)d_in[1];     // [2, E] int
  const float* ew = (const float*)d_in[2];
  const float* W1 = (const float*)d_in[3];
  const float* b1 = (const float*)d_in[4];
  const float* W2 = (const float*)d_in[5];
  const float* b2 = (const float*)d_in[6];
  float* out = (float*)d_out;

  const int N = NNODES, E = NEDGES, EP = NNODES + NEDGES;

  char* p = (char*)d_ws;
  auto alloc = [&](size_t bytes) { char* r = p; p += (bytes + 255) & ~(size_t)255; return r; };
  unsigned int* gbin   = (unsigned int*)alloc(256 * 4);
  unsigned int* binoff = (unsigned int*)alloc(256 * 4);
  unsigned int* gclaim = (unsigned int*)alloc(256 * 4);
  float* dinv   = (float*)alloc((size_t)N * 4);
  int*   offs   = (int*)  alloc((size_t)(N + 1) * 4);
  unsigned long long* binned = (unsigned long long*)alloc((size_t)E * 8);
  unsigned int* edges  = (unsigned int*)alloc((size_t)EP * 4);
  unsigned short* xw = (unsigned short*)alloc((size_t)N * HID_C * 2); // bf16 pre-agg / h2
  unsigned short* h  = (unsigned short*)alloc((size_t)N * HID_C * 2); // bf16 layer-1 out
  unsigned short* W1th = (unsigned short*)alloc((size_t)IN_C * HID_C * 2);
  unsigned short* W1tl = (unsigned short*)alloc((size_t)IN_C * HID_C * 2);
  unsigned short* W2th = (unsigned short*)alloc((size_t)HID_C * OUT_C * 2);
  unsigned short* W2tl = (unsigned short*)alloc((size_t)HID_C * OUT_C * 2);

  // prep0: zero gbin + wsplit W1,W2
  const int PREP0 = 256 + IN_C * HID_C + HID_C * OUT_C;
  prep0_kernel<<<(PREP0 + 255) / 256, 256, 0, stream>>>(
      gbin, W1, W1th, W1tl, W2, W2th, W2tl);

  const int NBLKE = (E + 8191) / 8192;   // 98
  bin_hist_kernel<<<NBLKE, 1024, 0, stream>>>(ei, gbin, E);
  bin_scan_kernel<<<1, 256, 0, stream>>>(gbin, binoff, gclaim);
  bin_scatter_kernel<<<NBLKE, 1024, 0, stream>>>(ei, ew, gclaim, binned, E);

  // layer 1 GEMM: xw = bf16(x @ W1)   [BM=128, N=128, 8 waves]
  gemm_mfma_kernel<IN_C, HID_C, 4, 2><<<(N + 127) / 128, 512, 0, stream>>>(x, W1th, W1tl, xw, N);

  bucket_deg_kernel<<<NBUCK, 256, 0, stream>>>(binned, binoff, dinv, offs);
  bucket_fill_kernel<<<NBUCK, 256, 0, stream>>>(binned, binoff, dinv, offs, edges);

  // layer 1 agg: h = bf16(relu(agg(xw) + b1))
  agg_kernel<HID_C, true, true><<<(N + 15) / 16, 256, 0, stream>>>(xw, offs, edges, b1, h, N);

  // layer 2: h2 = bf16(h @ W2)  [bf16-A GEMM, BM=256, N=64, 8 waves]
  gemm_bf16a_kernel<HID_C, OUT_C, 8, 1><<<(N + 255) / 256, 512, 0, stream>>>(h, W2th, W2tl, xw, N);
  agg_kernel<OUT_C, false, false><<<(N + 31) / 32, 256, 0, stream>>>(xw, offs, edges, b2, out, N);
}

// Round 15
// 117.407 us; speedup vs baseline: 1.3962x; 1.0625x over previous
//
#include <hip/hip_runtime.h>

#define NNODES 50000
#define NEDGES 800000
#define IN_C   512
#define HID_C  128
#define OUT_C  64
#define NBUCK  196        // bucket = dest >> 8
#define BCAP   5120       // fixed bucket capacity (mean 4096, sigma 64 -> +16 sigma)
#define BREG   5376       // padded CSR region per bucket (BCAP + 256 self-loops)

typedef float  f32x4  __attribute__((ext_vector_type(4)));
typedef __bf16 bf16x8 __attribute__((ext_vector_type(8)));
typedef short  short8 __attribute__((ext_vector_type(8)));

#define GLDS(src, dst) \
  __builtin_amdgcn_global_load_lds( \
      (const __attribute__((address_space(1))) unsigned int*)(src), \
      (__attribute__((address_space(3))) unsigned int*)(dst), 16, 0, 0)

__device__ __forceinline__ float bf2f(unsigned short u) {
  unsigned int x = (unsigned int)u << 16;
  return __builtin_bit_cast(float, x);
}
__device__ __forceinline__ unsigned short f16bits(float f) {
  _Float16 h = (_Float16)f;
  return __builtin_bit_cast(unsigned short, h);
}
__device__ __forceinline__ float f16val(unsigned short u) {
  return (float)__builtin_bit_cast(_Float16, u);
}

// ---------------- prep0: seed claim cursors + split/transpose W1,W2 ----------------

__device__ __forceinline__ void wsplit_one(const float* __restrict__ W,
                                           unsigned short* __restrict__ Th,
                                           unsigned short* __restrict__ Tl,
                                           int K, int N, int id) {
  int k = id % K, n = id / K;           // consecutive id -> consecutive k (coalesced writes)
  float f = W[(size_t)k * N + n];
  __bf16 hb = (__bf16)f;
  __bf16 lb = (__bf16)(f - (float)hb);
  Th[id] = __builtin_bit_cast(unsigned short, hb);
  Tl[id] = __builtin_bit_cast(unsigned short, lb);
}

__global__ void __launch_bounds__(256) prep0_kernel(
    unsigned int* __restrict__ gclaim,
    const float* __restrict__ W1, unsigned short* __restrict__ W1th,
    unsigned short* __restrict__ W1tl,
    const float* __restrict__ W2, unsigned short* __restrict__ W2th,
    unsigned short* __restrict__ W2tl) {
  int id = blockIdx.x * blockDim.x + threadIdx.x;
  if (id < 256) { if (id < NBUCK) gclaim[id] = (unsigned int)id * BCAP; return; }
  int s = id - 256;
  if (s < IN_C * HID_C) wsplit_one(W1, W1th, W1tl, IN_C, HID_C, s);
  else if (s < IN_C * HID_C + HID_C * OUT_C)
    wsplit_one(W2, W2th, W2tl, HID_C, OUT_C, s - IN_C * HID_C);
}

// ---------------- B1: single-pass scatter into fixed-capacity buckets ----------------
// per-block LDS histogram -> ONE returning atomic per (block,bin) claims a range ->
// per-bin consecutive writes. Record u64: src:16 | dest_lo:8 | f16(ew):16.
// Final gclaim[b] - b*BCAP == bucket b's edge count (consumed by bucket_deg).

__global__ void __launch_bounds__(1024) bin_scatter_kernel(
    const int* __restrict__ ei, const float* __restrict__ ew,
    unsigned int* __restrict__ gclaim, unsigned long long* __restrict__ binned, int nE) {
  __shared__ unsigned int h[NBUCK];
  __shared__ unsigned int cur[NBUCK];
  int t = threadIdx.x;
  if (t < NBUCK) h[t] = 0;
  __syncthreads();
  int base = blockIdx.x * 8192;
  int r[8]; unsigned int c[8]; unsigned short wb[8];
#pragma unroll
  for (int i = 0; i < 8; ++i) {
    int e = base + i * 1024 + t;
    if (e < nE) {
      r[i] = ei[e];
      c[i] = (unsigned int)ei[nE + e];
      wb[i] = f16bits(ew[e]);
      atomicAdd(&h[c[i] >> 8], 1u);
    } else {
      c[i] = 0xFFFFFFFFu;
    }
  }
  __syncthreads();
  if (t < NBUCK) cur[t] = h[t] ? atomicAdd(&gclaim[t], h[t]) : 0u;
  __syncthreads();
#pragma unroll
  for (int i = 0; i < 8; ++i) {
    if (c[i] != 0xFFFFFFFFu) {
      unsigned int pos = atomicAdd(&cur[c[i] >> 8], 1u);
      unsigned long long rec = (unsigned long long)((unsigned int)r[i] & 0xFFFFu)
                             | ((unsigned long long)(c[i] & 0xFFu) << 16)
                             | ((unsigned long long)wb[i] << 32);
      binned[pos] = rec;
    }
  }
}

// ---------------- B2a: per-bucket deg/dinv/offs/cnt (LDS atomics, deterministic) ----

__global__ void __launch_bounds__(256) bucket_deg_kernel(
    const unsigned long long* __restrict__ binned, const unsigned int* __restrict__ gclaim,
    float* __restrict__ dinv, int* __restrict__ offs, unsigned short* __restrict__ cnts) {
  int b = blockIdx.x, t = threadIdx.x;
  int base = b * BCAP;
  int cnt = (int)gclaim[b] - base;
  int nb = min(256, NNODES - b * 256);
  __shared__ unsigned int ec[256], wf[256];
  __shared__ int sc[256];
  ec[t] = 0; wf[t] = 0;
  __syncthreads();
  for (int i = t; i < cnt; i += 256) {
    unsigned long long rec = binned[base + i];
    int dlo = (int)((rec >> 16) & 255ULL);
    atomicAdd(&ec[dlo], 1u);
    float w = f16val((unsigned short)(rec >> 32));
    atomicAdd(&wf[dlo], (unsigned int)(w * 1048576.0f + 0.5f));   // fixed-point 2^20
  }
  __syncthreads();
  int cn = (t < nb) ? (int)ec[t] + 1 : 0;   // + self-loop slot
  sc[t] = cn;
  __syncthreads();
  for (int off = 1; off < 256; off <<= 1) {
    int u = (t >= off) ? sc[t - off] : 0;
    __syncthreads();
    sc[t] += u;
    __syncthreads();
  }
  if (t < nb) {
    float deg = (float)wf[t] * (1.0f / 1048576.0f) + 1.0f;   // + self-loop w=1
    int g = b * 256 + t;
    dinv[g] = rsqrtf(deg);
    offs[g] = b * BREG + sc[t] - cn;
    cnts[g] = (unsigned short)ec[t];
  }
}

// ---------------- B2b: per-bucket normalize + CSR build in LDS + coalesced out ----------
// final record u32: src:16 | f16(dinv[src]*ew*dinv[dest]):16

__global__ void __launch_bounds__(256) bucket_fill_kernel(
    const unsigned long long* __restrict__ binned, const unsigned int* __restrict__ gclaim,
    const float* __restrict__ dinv, const int* __restrict__ offs,
    unsigned int* __restrict__ edges) {
  int b = blockIdx.x, t = threadIdx.x;
  int base = b * BCAP;
  int cnt = (int)gclaim[b] - base;
  int nb = min(256, NNODES - b * 256);
  int csrbase = b * BREG;
  __shared__ unsigned int image[BREG];
  __shared__ unsigned int cur[256];
  __shared__ float ldv[256];
  float di = 0.f;
  if (t < nb) {
    int g = b * 256 + t;
    di = dinv[g];
    int loc = offs[g] - csrbase;
    cur[t] = (unsigned int)(loc + 1);
    image[loc] = (unsigned int)g | ((unsigned int)f16bits(di * di) << 16);  // self-loop
  }
  ldv[t] = di;
  __syncthreads();
  for (int i = t; i < cnt; i += 256) {
    unsigned long long rec = binned[base + i];
    int src = (int)(rec & 0xFFFFULL);
    int dlo = (int)((rec >> 16) & 255ULL);
    float w = f16val((unsigned short)(rec >> 32));
    float nm = dinv[src] * w * ldv[dlo];
    unsigned int pos = atomicAdd(&cur[dlo], 1u);
    image[pos] = (unsigned int)src | ((unsigned int)f16bits(nm) << 16);
  }
  __syncthreads();
  int total = cnt + nb;
  for (int j = t; j < total; j += 256) edges[csrbase + j] = image[j];
}

// ---------------- f32-A split-bf16 MFMA GEMM (layer 1) ----------------
// Y[M,N] = X[M,K] @ W[K,N] -> bf16 (RNE);  Y ~= Xh@Wh + Xl@Wh + Xh@Wl
template <int K, int N, int WR, int WC>
__global__ void __launch_bounds__(WR * WC * 64, 4) gemm_mfma_kernel(
    const float* __restrict__ X, const unsigned short* __restrict__ Bth,
    const unsigned short* __restrict__ Btl, unsigned short* __restrict__ Y, int M) {
  constexpr int NW = WR * WC;
  constexpr int BM = WR * 32;
  constexpr int NI = K / 32;
  constexpr int ASLOTS = (BM / 8) / NW;
  constexpr int BSLOTS = (N / 8) / NW;

  __shared__ float          As[2][BM * 32];
  __shared__ unsigned short Bs[2][2][N * 32];

  int tid = threadIdx.x;
  int lane = tid & 63, wid = tid >> 6;
  int wr = wid / WC, wc = wid % WC;
  int row0blk = blockIdx.x * BM;
  int row0 = row0blk + wr * 32;
  int rlo = lane & 15;
  int khi = lane >> 4;

  f32x4 acc[2][4] = {};

  auto stage = [&](int t, int buf) {
    int kb = t * 32;
#pragma unroll
    for (int i = 0; i < ASLOTS; ++i) {
      int slot = wid * ASLOTS + i;
      int rt = slot * 8 + (lane >> 3);
      int gr = row0blk + rt; gr = gr < M ? gr : M - 1;
      int gs = (lane & 7) ^ (lane >> 3);
      GLDS(X + (size_t)gr * K + kb + gs * 4, &As[buf][slot * 256]);
    }
#pragma unroll
    for (int i = 0; i < BSLOTS; ++i) {
      int slot = wid * BSLOTS + i;
      int half = slot / (N / 16);
      int idx = slot % (N / 16);
      const unsigned short* Wt = half ? Btl : Bth;
      int c = idx * 16 + (lane >> 2);
      int gs = (lane & 3) ^ (lane >> 4);
      GLDS(Wt + (size_t)c * K + kb + gs * 8, &Bs[buf][half][idx * 512]);
    }
  };

  stage(0, 0);
  __syncthreads();

#pragma unroll 1
  for (int t = 0; t < NI; ++t) {
    int buf = t & 1;
    if (t + 1 < NI) stage(t + 1, buf ^ 1);

    bf16x8 ah[2], al[2];
#pragma unroll
    for (int m = 0; m < 2; ++m) {
      int rt = wr * 32 + m * 16 + rlo;
      int p0 = (khi * 2) ^ (rlo & 7), p1 = (khi * 2 + 1) ^ (rlo & 7);
      f32x4 v0 = *reinterpret_cast<const f32x4*>(&As[buf][rt * 32 + p0 * 4]);
      f32x4 v1 = *reinterpret_cast<const f32x4*>(&As[buf][rt * 32 + p1 * 4]);
      float f[8] = {v0.x, v0.y, v0.z, v0.w, v1.x, v1.y, v1.z, v1.w};
#pragma unroll
      for (int i = 0; i < 8; ++i) {
        __bf16 hv = (__bf16)f[i];
        ah[m][i] = hv;
        al[m][i] = (__bf16)(f[i] - (float)hv);
      }
    }
    short8 bh[4], bl[4];
#pragma unroll
    for (int n = 0; n < 4; ++n) {
      int c = wc * 64 + n * 16 + rlo;
      int pos = khi ^ (rlo >> 2);
      bh[n] = *reinterpret_cast<const short8*>(&Bs[buf][0][c * 32 + pos * 8]);
      bl[n] = *reinterpret_cast<const short8*>(&Bs[buf][1][c * 32 + pos * 8]);
    }
#pragma unroll
    for (int m = 0; m < 2; ++m)
#pragma unroll
      for (int n = 0; n < 4; ++n)
        acc[m][n] = __builtin_amdgcn_mfma_f32_16x16x32_bf16(
            ah[m], __builtin_bit_cast(bf16x8, bh[n]), acc[m][n], 0, 0, 0);
#pragma unroll
    for (int m = 0; m < 2; ++m)
#pragma unroll
      for (int n = 0; n < 4; ++n)
        acc[m][n] = __builtin_amdgcn_mfma_f32_16x16x32_bf16(
            al[m], __builtin_bit_cast(bf16x8, bh[n]), acc[m][n], 0, 0, 0);
#pragma unroll
    for (int m = 0; m < 2; ++m)
#pragma unroll
      for (int n = 0; n < 4; ++n)
        acc[m][n] = __builtin_amdgcn_mfma_f32_16x16x32_bf16(
            ah[m], __builtin_bit_cast(bf16x8, bl[n]), acc[m][n], 0, 0, 0);
    __syncthreads();
  }

  // C/D: col = lane&15, row = (lane>>4)*4 + reg; store bf16 (RNE)
#pragma unroll
  for (int m = 0; m < 2; ++m)
#pragma unroll
    for (int j = 0; j < 4; ++j) {
      int row = row0 + m * 16 + khi * 4 + j;
      if (row < M) {
#pragma unroll
        for (int n = 0; n < 4; ++n) {
          __bf16 q = (__bf16)acc[m][n][j];
          Y[(size_t)row * N + wc * 64 + n * 16 + rlo] = __builtin_bit_cast(unsigned short, q);
        }
      }
    }
}

// ---------------- bf16-A MFMA GEMM (layer 2): A already bf16 -> 2 MFMA terms ----------------
template <int K, int N, int WR, int WC>
__global__ void __launch_bounds__(WR * WC * 64, 4) gemm_bf16a_kernel(
    const unsigned short* __restrict__ X, const unsigned short* __restrict__ Bth,
    const unsigned short* __restrict__ Btl, unsigned short* __restrict__ Y, int M) {
  constexpr int NW = WR * WC;
  constexpr int BM = WR * 32;
  constexpr int NI = K / 32;
  constexpr int ASLOTS = (BM / 16) / NW;
  constexpr int BSLOTS = (N / 8) / NW;

  __shared__ unsigned short As[2][BM * 32];
  __shared__ unsigned short Bs[2][2][N * 32];

  int tid = threadIdx.x;
  int lane = tid & 63, wid = tid >> 6;
  int wr = wid / WC, wc = wid % WC;
  int row0blk = blockIdx.x * BM;
  int row0 = row0blk + wr * 32;
  int rlo = lane & 15;
  int khi = lane >> 4;

  f32x4 acc[2][4] = {};

  auto stage = [&](int t, int buf) {
    int kb = t * 32;
#pragma unroll
    for (int i = 0; i < ASLOTS; ++i) {
      int slot = wid * ASLOTS + i;
      int rt = slot * 16 + (lane >> 2);
      int gr = row0blk + rt; gr = gr < M ? gr : M - 1;
      int gs = (lane & 3) ^ ((lane >> 3) & 3);
      GLDS(X + (size_t)gr * K + kb + gs * 8, &As[buf][slot * 512]);
    }
#pragma unroll
    for (int i = 0; i < BSLOTS; ++i) {
      int slot = wid * BSLOTS + i;
      int half = slot / (N / 16);
      int idx = slot % (N / 16);
      const unsigned short* Wt = half ? Btl : Bth;
      int c = idx * 16 + (lane >> 2);
      int gs = (lane & 3) ^ (lane >> 4);
      GLDS(Wt + (size_t)c * K + kb + gs * 8, &Bs[buf][half][idx * 512]);
    }
  };

  stage(0, 0);
  __syncthreads();

#pragma unroll 1
  for (int t = 0; t < NI; ++t) {
    int buf = t & 1;
    if (t + 1 < NI) stage(t + 1, buf ^ 1);

    short8 ah[2];
#pragma unroll
    for (int m = 0; m < 2; ++m) {
      int rt = wr * 32 + m * 16 + rlo;
      int g = khi ^ ((rt >> 1) & 3);
      ah[m] = *reinterpret_cast<const short8*>(&As[buf][rt * 32 + g * 8]);
    }
    short8 bh[4], bl[4];
#pragma unroll
    for (int n = 0; n < 4; ++n) {
      int c = wc * 64 + n * 16 + rlo;
      int pos = khi ^ (rlo >> 2);
      bh[n] = *reinterpret_cast<const short8*>(&Bs[buf][0][c * 32 + pos * 8]);
      bl[n] = *reinterpret_cast<const short8*>(&Bs[buf][1][c * 32 + pos * 8]);
    }
#pragma unroll
    for (int m = 0; m < 2; ++m)
#pragma unroll
      for (int n = 0; n < 4; ++n)
        acc[m][n] = __builtin_amdgcn_mfma_f32_16x16x32_bf16(
            __builtin_bit_cast(bf16x8, ah[m]), __builtin_bit_cast(bf16x8, bh[n]),
            acc[m][n], 0, 0, 0);
#pragma unroll
    for (int m = 0; m < 2; ++m)
#pragma unroll
      for (int n = 0; n < 4; ++n)
        acc[m][n] = __builtin_amdgcn_mfma_f32_16x16x32_bf16(
            __builtin_bit_cast(bf16x8, ah[m]), __builtin_bit_cast(bf16x8, bl[n]),
            acc[m][n], 0, 0, 0);
    __syncthreads();
  }

#pragma unroll
  for (int m = 0; m < 2; ++m)
#pragma unroll
    for (int j = 0; j < 4; ++j) {
      int row = row0 + m * 16 + khi * 4 + j;
      if (row < M) {
#pragma unroll
        for (int n = 0; n < 4; ++n) {
          __bf16 q = (__bf16)acc[m][n][j];
          Y[(size_t)row * N + wc * 64 + n * 16 + rlo] = __builtin_bit_cast(unsigned short, q);
        }
      }
    }
}

// ---------------- CSR aggregation over bf16 features, feature-sliced ----------------
// Processes FSLICE features starting at foff of an FSTRIDE-wide table. Slicing shrinks the
// gather working set (12.8 -> 6.4MB for layer 1) to ~fit per-XCD L2; each request = 1 line.
// e1 = e0 + 1 + cnts[node] (padded CSR has no valid offs[node+1] at bucket boundaries).
template <int FSLICE, int FSTRIDE, bool RELU, bool OUTBF>
__global__ void __launch_bounds__(256) agg_kernel(const unsigned short* __restrict__ feat,
                                                  const int* __restrict__ offs,
                                                  const unsigned short* __restrict__ cnts,
                                                  const unsigned int* __restrict__ edges,
                                                  const float* __restrict__ bias,
                                                  void* __restrict__ outv, int foff, int n) {
  constexpr int LPN = FSLICE / 8;
  constexpr int NPW = 64 / LPN;
  constexpr int NPB = 4 * NPW;
  int wid = threadIdx.x >> 6;
  int lane = threadIdx.x & 63;
  int node = blockIdx.x * NPB + wid * NPW + lane / LPN;
  int lf = (lane % LPN) * 8;
  if (node >= n) return;
  int e0 = offs[node];
  int e1 = e0 + 1 + (int)cnts[node];
  const unsigned short* fp = feat + foff + lf;

  float acc[8];
#pragma unroll
  for (int j = 0; j < 8; ++j) acc[j] = bias[foff + lf + j];

  auto fmaEdge = [&](unsigned int q) {
    float w = f16val((unsigned short)(q >> 16));
    int row = (int)(q & 0xFFFFu);
    short8 v = *reinterpret_cast<const short8*>(fp + (size_t)row * FSTRIDE);
#pragma unroll
    for (int j = 0; j < 8; ++j)
      acc[j] = fmaf(w, bf2f((unsigned short)v[j]), acc[j]);
  };

  int e = e0;
  for (; e + 4 <= e1; e += 4) {
    unsigned int q0 = edges[e], q1 = edges[e + 1], q2 = edges[e + 2], q3 = edges[e + 3];
    fmaEdge(q0); fmaEdge(q1); fmaEdge(q2); fmaEdge(q3);
  }
  for (; e < e1; ++e) fmaEdge(edges[e]);

  if (RELU) {
#pragma unroll
    for (int j = 0; j < 8; ++j) acc[j] = fmaxf(acc[j], 0.f);
  }
  if constexpr (OUTBF) {
    short8 o;
#pragma unroll
    for (int j = 0; j < 8; ++j) {
      __bf16 q = (__bf16)acc[j];
      o[j] = (short)__builtin_bit_cast(unsigned short, q);
    }
    *reinterpret_cast<short8*>((unsigned short*)outv + (size_t)node * FSTRIDE + foff + lf) = o;
  } else {
    float* out = (float*)outv;
    float4 o0 = make_float4(acc[0], acc[1], acc[2], acc[3]);
    float4 o1 = make_float4(acc[4], acc[5], acc[6], acc[7]);
    *reinterpret_cast<float4*>(&out[(size_t)node * FSTRIDE + foff + lf]) = o0;
    *reinterpret_cast<float4*>(&out[(size_t)node * FSTRIDE + foff + lf + 4]) = o1;
  }
}

// ---------------- launch ----------------

extern "C" void kernel_launch(void* const* d_in, const int* in_sizes, int n_in,
                              void* d_out, int out_size, void* d_ws, size_t ws_size,
                              hipStream_t stream) {
  const float* x  = (const float*)d_in[0];
  const int*   ei = (const int*)d_in[1];     // [2, E] int
  const float* ew = (const float*)d_in[2];
  const float* W1 = (const float*)d_in[3];
  const float* b1 = (const float*)d_in[4];
  const float* W2 = (const float*)d_in[5];
  const float* b2 = (const float*)d_in[6];
  float* out = (float*)d_out;

  const int N = NNODES, E = NEDGES;

  char* p = (char*)d_ws;
  auto alloc = [&](size_t bytes) { char* r = p; p += (bytes + 255) & ~(size_t)255; return r; };
  unsigned int* gclaim = (unsigned int*)alloc(256 * 4);
  float* dinv   = (float*)alloc((size_t)N * 4);
  int*   offs   = (int*)  alloc((size_t)N * 4);
  unsigned short* cnts = (unsigned short*)alloc((size_t)N * 2);
  unsigned long long* binned = (unsigned long long*)alloc((size_t)NBUCK * BCAP * 8);
  unsigned int* edges  = (unsigned int*)alloc((size_t)NBUCK * BREG * 4);
  unsigned short* xw = (unsigned short*)alloc((size_t)N * HID_C * 2); // bf16 pre-agg / h2
  unsigned short* h  = (unsigned short*)alloc((size_t)N * HID_C * 2); // bf16 layer-1 out
  unsigned short* W1th = (unsigned short*)alloc((size_t)IN_C * HID_C * 2);
  unsigned short* W1tl = (unsigned short*)alloc((size_t)IN_C * HID_C * 2);
  unsigned short* W2th = (unsigned short*)alloc((size_t)HID_C * OUT_C * 2);
  unsigned short* W2tl = (unsigned short*)alloc((size_t)HID_C * OUT_C * 2);

  // prep0: seed gclaim (bucket cursors) + wsplit W1,W2
  const int PREP0 = 256 + IN_C * HID_C + HID_C * OUT_C;
  prep0_kernel<<<(PREP0 + 255) / 256, 256, 0, stream>>>(
      gclaim, W1, W1th, W1tl, W2, W2th, W2tl);

  const int NBLKE = (E + 8191) / 8192;   // 98
  bin_scatter_kernel<<<NBLKE, 1024, 0, stream>>>(ei, ew, gclaim, binned, E);

  // layer 1 GEMM: xw = bf16(x @ W1)   [BM=128, N=128, 8 waves]
  gemm_mfma_kernel<IN_C, HID_C, 4, 2><<<(N + 127) / 128, 512, 0, stream>>>(x, W1th, W1tl, xw, N);

  bucket_deg_kernel<<<NBUCK, 256, 0, stream>>>(binned, gclaim, dinv, offs, cnts);
  bucket_fill_kernel<<<NBUCK, 256, 0, stream>>>(binned, gclaim, dinv, offs, edges);

  // layer 1 agg: h = bf16(relu(agg(xw) + b1)) — two 64-feature slices for L2 locality
  agg_kernel<64, HID_C, true, true><<<(N + 31) / 32, 256, 0, stream>>>(
      xw, offs, cnts, edges, b1, h, 0, N);
  agg_kernel<64, HID_C, true, true><<<(N + 31) / 32, 256, 0, stream>>>(
      xw, offs, cnts, edges, b1, h, 64, N);

  // layer 2: h2 = bf16(h @ W2)  [bf16-A GEMM, BM=256, N=64, 8 waves]
  gemm_bf16a_kernel<HID_C, OUT_C, 8, 1><<<(N + 255) / 256, 512, 0, stream>>>(h, W2th, W2tl, xw, N);
  agg_kernel<64, OUT_C, false, false><<<(N + 31) / 32, 256, 0, stream>>>(
      xw, offs, cnts, edges, b2, out, 0, N);
}

// Round 16
// 107.308 us; speedup vs baseline: 1.5276x; 1.0941x over previous
//
#include <hip/hip_runtime.h>

#define NNODES 50000
#define NEDGES 800000
#define IN_C   512
#define HID_C  128
#define OUT_C  64
#define NBUCK  196        // bucket = dest >> 8
#define BCAP   5120       // fixed bucket capacity (mean 4096, sigma 64 -> +16 sigma)
#define BREG   5376       // padded CSR region per bucket (BCAP + 256 self-loops)

typedef float  f32x4  __attribute__((ext_vector_type(4)));
typedef __bf16 bf16x8 __attribute__((ext_vector_type(8)));
typedef short  short8 __attribute__((ext_vector_type(8)));

#define GLDS(src, dst) \
  __builtin_amdgcn_global_load_lds( \
      (const __attribute__((address_space(1))) unsigned int*)(src), \
      (__attribute__((address_space(3))) unsigned int*)(dst), 16, 0, 0)

__device__ __forceinline__ float bf2f(unsigned short u) {
  unsigned int x = (unsigned int)u << 16;
  return __builtin_bit_cast(float, x);
}
__device__ __forceinline__ unsigned short f16bits(float f) {
  _Float16 h = (_Float16)f;
  return __builtin_bit_cast(unsigned short, h);
}
__device__ __forceinline__ float f16val(unsigned short u) {
  return (float)__builtin_bit_cast(_Float16, u);
}

// ---------------- prep0: seed claim cursors + split/transpose W1,W2 ----------------

__device__ __forceinline__ void wsplit_one(const float* __restrict__ W,
                                           unsigned short* __restrict__ Th,
                                           unsigned short* __restrict__ Tl,
                                           int K, int N, int id) {
  int k = id % K, n = id / K;           // consecutive id -> consecutive k (coalesced writes)
  float f = W[(size_t)k * N + n];
  __bf16 hb = (__bf16)f;
  __bf16 lb = (__bf16)(f - (float)hb);
  Th[id] = __builtin_bit_cast(unsigned short, hb);
  Tl[id] = __builtin_bit_cast(unsigned short, lb);
}

__global__ void __launch_bounds__(256) prep0_kernel(
    unsigned int* __restrict__ gclaim,
    const float* __restrict__ W1, unsigned short* __restrict__ W1th,
    unsigned short* __restrict__ W1tl,
    const float* __restrict__ W2, unsigned short* __restrict__ W2th,
    unsigned short* __restrict__ W2tl) {
  int id = blockIdx.x * blockDim.x + threadIdx.x;
  if (id < 256) { if (id < NBUCK) gclaim[id] = (unsigned int)id * BCAP; return; }
  int s = id - 256;
  if (s < IN_C * HID_C) wsplit_one(W1, W1th, W1tl, IN_C, HID_C, s);
  else if (s < IN_C * HID_C + HID_C * OUT_C)
    wsplit_one(W2, W2th, W2tl, HID_C, OUT_C, s - IN_C * HID_C);
}

// ---------------- f32-A split-bf16 MFMA GEMM body (layer 1) ----------------
// Y[M,N] = X[M,K] @ W[K,N] -> bf16 (RNE);  Y ~= Xh@Wh + Xl@Wh + Xh@Wl
// Per K-chunk (BK=32): A f32 + B=W^T hi/lo bf16 staged via global_load_lds, dbuf,
// one barrier per chunk. Source-swizzled / read-unswizzled (rule #21).
template <int K, int N, int WR, int WC>
__device__ __forceinline__ void gemm_body(const float* __restrict__ X,
                                          const unsigned short* __restrict__ Bth,
                                          const unsigned short* __restrict__ Btl,
                                          unsigned short* __restrict__ Y, int M, int bid) {
  constexpr int NW = WR * WC;
  constexpr int BM = WR * 32;
  constexpr int NI = K / 32;
  constexpr int ASLOTS = (BM / 8) / NW;
  constexpr int BSLOTS = (N / 8) / NW;

  __shared__ float          As[2][BM * 32];
  __shared__ unsigned short Bs[2][2][N * 32];

  int tid = threadIdx.x;
  int lane = tid & 63, wid = tid >> 6;
  int wr = wid / WC, wc = wid % WC;
  int row0blk = bid * BM;
  int row0 = row0blk + wr * 32;
  int rlo = lane & 15;
  int khi = lane >> 4;

  f32x4 acc[2][4] = {};

  auto stage = [&](int t, int buf) {
    int kb = t * 32;
#pragma unroll
    for (int i = 0; i < ASLOTS; ++i) {
      int slot = wid * ASLOTS + i;
      int rt = slot * 8 + (lane >> 3);
      int gr = row0blk + rt; gr = gr < M ? gr : M - 1;
      int gs = (lane & 7) ^ (lane >> 3);
      GLDS(X + (size_t)gr * K + kb + gs * 4, &As[buf][slot * 256]);
    }
#pragma unroll
    for (int i = 0; i < BSLOTS; ++i) {
      int slot = wid * BSLOTS + i;
      int half = slot / (N / 16);
      int idx = slot % (N / 16);
      const unsigned short* Wt = half ? Btl : Bth;
      int c = idx * 16 + (lane >> 2);
      int gs = (lane & 3) ^ (lane >> 4);
      GLDS(Wt + (size_t)c * K + kb + gs * 8, &Bs[buf][half][idx * 512]);
    }
  };

  stage(0, 0);
  __syncthreads();

#pragma unroll 1
  for (int t = 0; t < NI; ++t) {
    int buf = t & 1;
    if (t + 1 < NI) stage(t + 1, buf ^ 1);

    bf16x8 ah[2], al[2];
#pragma unroll
    for (int m = 0; m < 2; ++m) {
      int rt = wr * 32 + m * 16 + rlo;
      int p0 = (khi * 2) ^ (rlo & 7), p1 = (khi * 2 + 1) ^ (rlo & 7);
      f32x4 v0 = *reinterpret_cast<const f32x4*>(&As[buf][rt * 32 + p0 * 4]);
      f32x4 v1 = *reinterpret_cast<const f32x4*>(&As[buf][rt * 32 + p1 * 4]);
      float f[8] = {v0.x, v0.y, v0.z, v0.w, v1.x, v1.y, v1.z, v1.w};
#pragma unroll
      for (int i = 0; i < 8; ++i) {
        __bf16 hv = (__bf16)f[i];
        ah[m][i] = hv;
        al[m][i] = (__bf16)(f[i] - (float)hv);
      }
    }
    short8 bh[4], bl[4];
#pragma unroll
    for (int n = 0; n < 4; ++n) {
      int c = wc * 64 + n * 16 + rlo;
      int pos = khi ^ (rlo >> 2);
      bh[n] = *reinterpret_cast<const short8*>(&Bs[buf][0][c * 32 + pos * 8]);
      bl[n] = *reinterpret_cast<const short8*>(&Bs[buf][1][c * 32 + pos * 8]);
    }
#pragma unroll
    for (int m = 0; m < 2; ++m)
#pragma unroll
      for (int n = 0; n < 4; ++n)
        acc[m][n] = __builtin_amdgcn_mfma_f32_16x16x32_bf16(
            ah[m], __builtin_bit_cast(bf16x8, bh[n]), acc[m][n], 0, 0, 0);
#pragma unroll
    for (int m = 0; m < 2; ++m)
#pragma unroll
      for (int n = 0; n < 4; ++n)
        acc[m][n] = __builtin_amdgcn_mfma_f32_16x16x32_bf16(
            al[m], __builtin_bit_cast(bf16x8, bh[n]), acc[m][n], 0, 0, 0);
#pragma unroll
    for (int m = 0; m < 2; ++m)
#pragma unroll
      for (int n = 0; n < 4; ++n)
        acc[m][n] = __builtin_amdgcn_mfma_f32_16x16x32_bf16(
            ah[m], __builtin_bit_cast(bf16x8, bl[n]), acc[m][n], 0, 0, 0);
    __syncthreads();
  }

  // C/D: col = lane&15, row = (lane>>4)*4 + reg; store bf16 (RNE)
#pragma unroll
  for (int m = 0; m < 2; ++m)
#pragma unroll
    for (int j = 0; j < 4; ++j) {
      int row = row0 + m * 16 + khi * 4 + j;
      if (row < M) {
#pragma unroll
        for (int n = 0; n < 4; ++n) {
          __bf16 q = (__bf16)acc[m][n][j];
          Y[(size_t)row * N + wc * 64 + n * 16 + rlo] = __builtin_bit_cast(unsigned short, q);
        }
      }
    }
}

// ---------------- fused: gemm1 (blocks [0,ngemm)) ∥ bin_scatter (rest) ----------------
// Independent I/O. gemm1 at 2 blocks/CU can't fill the machine; scatter is memory-bound
// with only ~38k global atomics (LDS-aggregated) — round-13 lesson: fusion of such
// stages overlaps (the round-12 regression read was a duration-averaged-counters error).
// Scatter: 512 thr x 8 edges = 4096/block; record u64: src:16 | dest_lo:8 | f16(ew):16.
__global__ void __launch_bounds__(512, 4) fused_gemm1_scatter_kernel(
    const float* __restrict__ X, const unsigned short* __restrict__ Bth,
    const unsigned short* __restrict__ Btl, unsigned short* __restrict__ Y, int M,
    int ngemm, const int* __restrict__ ei, const float* __restrict__ ew,
    unsigned int* __restrict__ gclaim, unsigned long long* __restrict__ binned, int nE) {
  if ((int)blockIdx.x < ngemm) {
    gemm_body<IN_C, HID_C, 4, 2>(X, Bth, Btl, Y, M, blockIdx.x);
    return;
  }
  __shared__ unsigned int h[NBUCK];
  __shared__ unsigned int cur[NBUCK];
  int t = threadIdx.x;
  if (t < NBUCK) h[t] = 0;
  __syncthreads();
  int base = ((int)blockIdx.x - ngemm) * 4096;
  int r[8]; unsigned int c[8]; unsigned short wb[8];
#pragma unroll
  for (int i = 0; i < 8; ++i) {
    int e = base + i * 512 + t;
    if (e < nE) {
      r[i] = ei[e];
      c[i] = (unsigned int)ei[nE + e];
      wb[i] = f16bits(ew[e]);
      atomicAdd(&h[c[i] >> 8], 1u);
    } else {
      c[i] = 0xFFFFFFFFu;
    }
  }
  __syncthreads();
  if (t < NBUCK) cur[t] = h[t] ? atomicAdd(&gclaim[t], h[t]) : 0u;
  __syncthreads();
#pragma unroll
  for (int i = 0; i < 8; ++i) {
    if (c[i] != 0xFFFFFFFFu) {
      unsigned int pos = atomicAdd(&cur[c[i] >> 8], 1u);
      unsigned long long rec = (unsigned long long)((unsigned int)r[i] & 0xFFFFu)
                             | ((unsigned long long)(c[i] & 0xFFu) << 16)
                             | ((unsigned long long)wb[i] << 32);
      binned[pos] = rec;
    }
  }
}

// ---------------- B2a: per-bucket deg/dinv/offs/cnt (LDS atomics, deterministic) ----

__global__ void __launch_bounds__(256) bucket_deg_kernel(
    const unsigned long long* __restrict__ binned, const unsigned int* __restrict__ gclaim,
    float* __restrict__ dinv, int* __restrict__ offs, unsigned short* __restrict__ cnts) {
  int b = blockIdx.x, t = threadIdx.x;
  int base = b * BCAP;
  int cnt = (int)gclaim[b] - base;
  int nb = min(256, NNODES - b * 256);
  __shared__ unsigned int ec[256], wf[256];
  __shared__ int sc[256];
  ec[t] = 0; wf[t] = 0;
  __syncthreads();
  for (int i = t; i < cnt; i += 256) {
    unsigned long long rec = binned[base + i];
    int dlo = (int)((rec >> 16) & 255ULL);
    atomicAdd(&ec[dlo], 1u);
    float w = f16val((unsigned short)(rec >> 32));
    atomicAdd(&wf[dlo], (unsigned int)(w * 1048576.0f + 0.5f));   // fixed-point 2^20
  }
  __syncthreads();
  int cn = (t < nb) ? (int)ec[t] + 1 : 0;   // + self-loop slot
  sc[t] = cn;
  __syncthreads();
  for (int off = 1; off < 256; off <<= 1) {
    int u = (t >= off) ? sc[t - off] : 0;
    __syncthreads();
    sc[t] += u;
    __syncthreads();
  }
  if (t < nb) {
    float deg = (float)wf[t] * (1.0f / 1048576.0f) + 1.0f;   // + self-loop w=1
    int g = b * 256 + t;
    dinv[g] = rsqrtf(deg);
    offs[g] = b * BREG + sc[t] - cn;
    cnts[g] = (unsigned short)ec[t];
  }
}

// ---------------- B2b: per-bucket normalize + CSR build in LDS + coalesced out ----------
// final record u32: src:16 | f16(dinv[src]*ew*dinv[dest]):16

__global__ void __launch_bounds__(256) bucket_fill_kernel(
    const unsigned long long* __restrict__ binned, const unsigned int* __restrict__ gclaim,
    const float* __restrict__ dinv, const int* __restrict__ offs,
    unsigned int* __restrict__ edges) {
  int b = blockIdx.x, t = threadIdx.x;
  int base = b * BCAP;
  int cnt = (int)gclaim[b] - base;
  int nb = min(256, NNODES - b * 256);
  int csrbase = b * BREG;
  __shared__ unsigned int image[BREG];
  __shared__ unsigned int cur[256];
  __shared__ float ldv[256];
  float di = 0.f;
  if (t < nb) {
    int g = b * 256 + t;
    di = dinv[g];
    int loc = offs[g] - csrbase;
    cur[t] = (unsigned int)(loc + 1);
    image[loc] = (unsigned int)g | ((unsigned int)f16bits(di * di) << 16);  // self-loop
  }
  ldv[t] = di;
  __syncthreads();
  for (int i = t; i < cnt; i += 256) {
    unsigned long long rec = binned[base + i];
    int src = (int)(rec & 0xFFFFULL);
    int dlo = (int)((rec >> 16) & 255ULL);
    float w = f16val((unsigned short)(rec >> 32));
    float nm = dinv[src] * w * ldv[dlo];
    unsigned int pos = atomicAdd(&cur[dlo], 1u);
    image[pos] = (unsigned int)src | ((unsigned int)f16bits(nm) << 16);
  }
  __syncthreads();
  int total = cnt + nb;
  for (int j = t; j < total; j += 256) edges[csrbase + j] = image[j];
}

// ---------------- bf16-A MFMA GEMM (layer 2): A already bf16 -> 2 MFMA terms ----------------
template <int K, int N, int WR, int WC>
__global__ void __launch_bounds__(WR * WC * 64, 4) gemm_bf16a_kernel(
    const unsigned short* __restrict__ X, const unsigned short* __restrict__ Bth,
    const unsigned short* __restrict__ Btl, unsigned short* __restrict__ Y, int M) {
  constexpr int NW = WR * WC;
  constexpr int BM = WR * 32;
  constexpr int NI = K / 32;
  constexpr int ASLOTS = (BM / 16) / NW;
  constexpr int BSLOTS = (N / 8) / NW;

  __shared__ unsigned short As[2][BM * 32];
  __shared__ unsigned short Bs[2][2][N * 32];

  int tid = threadIdx.x;
  int lane = tid & 63, wid = tid >> 6;
  int wr = wid / WC, wc = wid % WC;
  int row0blk = blockIdx.x * BM;
  int row0 = row0blk + wr * 32;
  int rlo = lane & 15;
  int khi = lane >> 4;

  f32x4 acc[2][4] = {};

  auto stage = [&](int t, int buf) {
    int kb = t * 32;
#pragma unroll
    for (int i = 0; i < ASLOTS; ++i) {
      int slot = wid * ASLOTS + i;
      int rt = slot * 16 + (lane >> 2);
      int gr = row0blk + rt; gr = gr < M ? gr : M - 1;
      int gs = (lane & 3) ^ ((lane >> 3) & 3);
      GLDS(X + (size_t)gr * K + kb + gs * 8, &As[buf][slot * 512]);
    }
#pragma unroll
    for (int i = 0; i < BSLOTS; ++i) {
      int slot = wid * BSLOTS + i;
      int half = slot / (N / 16);
      int idx = slot % (N / 16);
      const unsigned short* Wt = half ? Btl : Bth;
      int c = idx * 16 + (lane >> 2);
      int gs = (lane & 3) ^ (lane >> 4);
      GLDS(Wt + (size_t)c * K + kb + gs * 8, &Bs[buf][half][idx * 512]);
    }
  };

  stage(0, 0);
  __syncthreads();

#pragma unroll 1
  for (int t = 0; t < NI; ++t) {
    int buf = t & 1;
    if (t + 1 < NI) stage(t + 1, buf ^ 1);

    short8 ah[2];
#pragma unroll
    for (int m = 0; m < 2; ++m) {
      int rt = wr * 32 + m * 16 + rlo;
      int g = khi ^ ((rt >> 1) & 3);
      ah[m] = *reinterpret_cast<const short8*>(&As[buf][rt * 32 + g * 8]);
    }
    short8 bh[4], bl[4];
#pragma unroll
    for (int n = 0; n < 4; ++n) {
      int c = wc * 64 + n * 16 + rlo;
      int pos = khi ^ (rlo >> 2);
      bh[n] = *reinterpret_cast<const short8*>(&Bs[buf][0][c * 32 + pos * 8]);
      bl[n] = *reinterpret_cast<const short8*>(&Bs[buf][1][c * 32 + pos * 8]);
    }
#pragma unroll
    for (int m = 0; m < 2; ++m)
#pragma unroll
      for (int n = 0; n < 4; ++n)
        acc[m][n] = __builtin_amdgcn_mfma_f32_16x16x32_bf16(
            __builtin_bit_cast(bf16x8, ah[m]), __builtin_bit_cast(bf16x8, bh[n]),
            acc[m][n], 0, 0, 0);
#pragma unroll
    for (int m = 0; m < 2; ++m)
#pragma unroll
      for (int n = 0; n < 4; ++n)
        acc[m][n] = __builtin_amdgcn_mfma_f32_16x16x32_bf16(
            __builtin_bit_cast(bf16x8, ah[m]), __builtin_bit_cast(bf16x8, bl[n]),
            acc[m][n], 0, 0, 0);
    __syncthreads();
  }

#pragma unroll
  for (int m = 0; m < 2; ++m)
#pragma unroll
    for (int j = 0; j < 4; ++j) {
      int row = row0 + m * 16 + khi * 4 + j;
      if (row < M) {
#pragma unroll
        for (int n = 0; n < 4; ++n) {
          __bf16 q = (__bf16)acc[m][n][j];
          Y[(size_t)row * N + wc * 64 + n * 16 + rlo] = __builtin_bit_cast(unsigned short, q);
        }
      }
    }
}

// ---------------- CSR aggregation over bf16 features ----------------
// e1 = e0 + 1 + cnts[node] (padded CSR). FSLICE = full width (slicing reverted: neutral).
template <int FSLICE, int FSTRIDE, bool RELU, bool OUTBF>
__global__ void __launch_bounds__(256) agg_kernel(const unsigned short* __restrict__ feat,
                                                  const int* __restrict__ offs,
                                                  const unsigned short* __restrict__ cnts,
                                                  const unsigned int* __restrict__ edges,
                                                  const float* __restrict__ bias,
                                                  void* __restrict__ outv, int foff, int n) {
  constexpr int LPN = FSLICE / 8;
  constexpr int NPW = 64 / LPN;
  constexpr int NPB = 4 * NPW;
  int wid = threadIdx.x >> 6;
  int lane = threadIdx.x & 63;
  int node = blockIdx.x * NPB + wid * NPW + lane / LPN;
  int lf = (lane % LPN) * 8;
  if (node >= n) return;
  int e0 = offs[node];
  int e1 = e0 + 1 + (int)cnts[node];
  const unsigned short* fp = feat + foff + lf;

  float acc[8];
#pragma unroll
  for (int j = 0; j < 8; ++j) acc[j] = bias[foff + lf + j];

  auto fmaEdge = [&](unsigned int q) {
    float w = f16val((unsigned short)(q >> 16));
    int row = (int)(q & 0xFFFFu);
    short8 v = *reinterpret_cast<const short8*>(fp + (size_t)row * FSTRIDE);
#pragma unroll
    for (int j = 0; j < 8; ++j)
      acc[j] = fmaf(w, bf2f((unsigned short)v[j]), acc[j]);
  };

  int e = e0;
  for (; e + 4 <= e1; e += 4) {
    unsigned int q0 = edges[e], q1 = edges[e + 1], q2 = edges[e + 2], q3 = edges[e + 3];
    fmaEdge(q0); fmaEdge(q1); fmaEdge(q2); fmaEdge(q3);
  }
  for (; e < e1; ++e) fmaEdge(edges[e]);

  if (RELU) {
#pragma unroll
    for (int j = 0; j < 8; ++j) acc[j] = fmaxf(acc[j], 0.f);
  }
  if constexpr (OUTBF) {
    short8 o;
#pragma unroll
    for (int j = 0; j < 8; ++j) {
      __bf16 q = (__bf16)acc[j];
      o[j] = (short)__builtin_bit_cast(unsigned short, q);
    }
    *reinterpret_cast<short8*>((unsigned short*)outv + (size_t)node * FSTRIDE + foff + lf) = o;
  } else {
    float* out = (float*)outv;
    float4 o0 = make_float4(acc[0], acc[1], acc[2], acc[3]);
    float4 o1 = make_float4(acc[4], acc[5], acc[6], acc[7]);
    *reinterpret_cast<float4*>(&out[(size_t)node * FSTRIDE + foff + lf]) = o0;
    *reinterpret_cast<float4*>(&out[(size_t)node * FSTRIDE + foff + lf + 4]) = o1;
  }
}

// ---------------- launch ----------------

extern "C" void kernel_launch(void* const* d_in, const int* in_sizes, int n_in,
                              void* d_out, int out_size, void* d_ws, size_t ws_size,
                              hipStream_t stream) {
  const float* x  = (const float*)d_in[0];
  const int*   ei = (const int*)d_in[1];     // [2, E] int
  const float* ew = (const float*)d_in[2];
  const float* W1 = (const float*)d_in[3];
  const float* b1 = (const float*)d_in[4];
  const float* W2 = (const float*)d_in[5];
  const float* b2 = (const float*)d_in[6];
  float* out = (float*)d_out;

  const int N = NNODES, E = NEDGES;

  char* p = (char*)d_ws;
  auto alloc = [&](size_t bytes) { char* r = p; p += (bytes + 255) & ~(size_t)255; return r; };
  unsigned int* gclaim = (unsigned int*)alloc(256 * 4);
  float* dinv   = (float*)alloc((size_t)N * 4);
  int*   offs   = (int*)  alloc((size_t)N * 4);
  unsigned short* cnts = (unsigned short*)alloc((size_t)N * 2);
  unsigned long long* binned = (unsigned long long*)alloc((size_t)NBUCK * BCAP * 8);
  unsigned int* edges  = (unsigned int*)alloc((size_t)NBUCK * BREG * 4);
  unsigned short* xw = (unsigned short*)alloc((size_t)N * HID_C * 2); // bf16 pre-agg / h2
  unsigned short* h  = (unsigned short*)alloc((size_t)N * HID_C * 2); // bf16 layer-1 out
  unsigned short* W1th = (unsigned short*)alloc((size_t)IN_C * HID_C * 2);
  unsigned short* W1tl = (unsigned short*)alloc((size_t)IN_C * HID_C * 2);
  unsigned short* W2th = (unsigned short*)alloc((size_t)HID_C * OUT_C * 2);
  unsigned short* W2tl = (unsigned short*)alloc((size_t)HID_C * OUT_C * 2);

  // prep0: seed gclaim (bucket cursors) + wsplit W1,W2
  const int PREP0 = 256 + IN_C * HID_C + HID_C * OUT_C;
  prep0_kernel<<<(PREP0 + 255) / 256, 256, 0, stream>>>(
      gclaim, W1, W1th, W1tl, W2, W2th, W2tl);

  // fused: gemm1 (391 blocks, xw = bf16(x @ W1)) ∥ bin_scatter (196 blocks)
  const int NGEMM = (N + 127) / 128;
  const int NSCAT = (E + 4095) / 4096;
  fused_gemm1_scatter_kernel<<<NGEMM + NSCAT, 512, 0, stream>>>(
      x, W1th, W1tl, xw, N, NGEMM, ei, ew, gclaim, binned, E);

  bucket_deg_kernel<<<NBUCK, 256, 0, stream>>>(binned, gclaim, dinv, offs, cnts);
  bucket_fill_kernel<<<NBUCK, 256, 0, stream>>>(binned, gclaim, dinv, offs, edges);

  // layer 1 agg: h = bf16(relu(agg(xw) + b1))
  agg_kernel<HID_C, HID_C, true, true><<<(N + 15) / 16, 256, 0, stream>>>(
      xw, offs, cnts, edges, b1, h, 0, N);

  // layer 2: h2 = bf16(h @ W2)  [bf16-A GEMM, BM=256, N=64, 8 waves]
  gemm_bf16a_kernel<HID_C, OUT_C, 8, 1><<<(N + 255) / 256, 512, 0, stream>>>(h, W2th, W2tl, xw, N);
  agg_kernel<OUT_C, OUT_C, false, false><<<(N + 31) / 32, 256, 0, stream>>>(
      xw, offs, cnts, edges, b2, out, 0, N);
}

// Round 17
// 106.751 us; speedup vs baseline: 1.5356x; 1.0052x over previous
//
#include <hip/hip_runtime.h>

#define NNODES 50000
#define NEDGES 800000
#define IN_C   512
#define HID_C  128
#define OUT_C  64
#define NBUCK  196        // bucket = dest >> 8
#define BCAP   5120       // fixed bucket capacity (mean 4096, sigma 64 -> +16 sigma)
#define BREG   5376       // padded CSR region per bucket (BCAP + 256 self-loops)

typedef float  f32x4  __attribute__((ext_vector_type(4)));
typedef __bf16 bf16x8 __attribute__((ext_vector_type(8)));
typedef short  short8 __attribute__((ext_vector_type(8)));

#define GLDS(src, dst) \
  __builtin_amdgcn_global_load_lds( \
      (const __attribute__((address_space(1))) unsigned int*)(src), \
      (__attribute__((address_space(3))) unsigned int*)(dst), 16, 0, 0)

__device__ __forceinline__ float bf2f(unsigned short u) {
  unsigned int x = (unsigned int)u << 16;
  return __builtin_bit_cast(float, x);
}
__device__ __forceinline__ unsigned short f16bits(float f) {
  _Float16 h = (_Float16)f;
  return __builtin_bit_cast(unsigned short, h);
}
__device__ __forceinline__ float f16val(unsigned short u) {
  return (float)__builtin_bit_cast(_Float16, u);
}

// ---------------- prep0: seed claim cursors + split/transpose W1,W2 ----------------

__device__ __forceinline__ void wsplit_one(const float* __restrict__ W,
                                           unsigned short* __restrict__ Th,
                                           unsigned short* __restrict__ Tl,
                                           int K, int N, int id) {
  int k = id % K, n = id / K;           // consecutive id -> consecutive k (coalesced writes)
  float f = W[(size_t)k * N + n];
  __bf16 hb = (__bf16)f;
  __bf16 lb = (__bf16)(f - (float)hb);
  Th[id] = __builtin_bit_cast(unsigned short, hb);
  Tl[id] = __builtin_bit_cast(unsigned short, lb);
}

__global__ void __launch_bounds__(256) prep0_kernel(
    unsigned int* __restrict__ gclaim,
    const float* __restrict__ W1, unsigned short* __restrict__ W1th,
    unsigned short* __restrict__ W1tl,
    const float* __restrict__ W2, unsigned short* __restrict__ W2th,
    unsigned short* __restrict__ W2tl) {
  int id = blockIdx.x * blockDim.x + threadIdx.x;
  if (id < 256) { if (id < NBUCK) gclaim[id] = (unsigned int)id * BCAP; return; }
  int s = id - 256;
  if (s < IN_C * HID_C) wsplit_one(W1, W1th, W1tl, IN_C, HID_C, s);
  else if (s < IN_C * HID_C + HID_C * OUT_C)
    wsplit_one(W2, W2th, W2tl, HID_C, OUT_C, s - IN_C * HID_C);
}

// ---------------- f32-A split-bf16 MFMA GEMM body (layer 1) ----------------
// Y[M,N] = X[M,K] @ W[K,N] -> bf16 (RNE);  Y ~= Xh@Wh + Xl@Wh + Xh@Wl
template <int K, int N, int WR, int WC>
__device__ __forceinline__ void gemm_body(const float* __restrict__ X,
                                          const unsigned short* __restrict__ Bth,
                                          const unsigned short* __restrict__ Btl,
                                          unsigned short* __restrict__ Y, int M, int bid) {
  constexpr int NW = WR * WC;
  constexpr int BM = WR * 32;
  constexpr int NI = K / 32;
  constexpr int ASLOTS = (BM / 8) / NW;
  constexpr int BSLOTS = (N / 8) / NW;

  __shared__ float          As[2][BM * 32];
  __shared__ unsigned short Bs[2][2][N * 32];

  int tid = threadIdx.x;
  int lane = tid & 63, wid = tid >> 6;
  int wr = wid / WC, wc = wid % WC;
  int row0blk = bid * BM;
  int row0 = row0blk + wr * 32;
  int rlo = lane & 15;
  int khi = lane >> 4;

  f32x4 acc[2][4] = {};

  auto stage = [&](int t, int buf) {
    int kb = t * 32;
#pragma unroll
    for (int i = 0; i < ASLOTS; ++i) {
      int slot = wid * ASLOTS + i;
      int rt = slot * 8 + (lane >> 3);
      int gr = row0blk + rt; gr = gr < M ? gr : M - 1;
      int gs = (lane & 7) ^ (lane >> 3);
      GLDS(X + (size_t)gr * K + kb + gs * 4, &As[buf][slot * 256]);
    }
#pragma unroll
    for (int i = 0; i < BSLOTS; ++i) {
      int slot = wid * BSLOTS + i;
      int half = slot / (N / 16);
      int idx = slot % (N / 16);
      const unsigned short* Wt = half ? Btl : Bth;
      int c = idx * 16 + (lane >> 2);
      int gs = (lane & 3) ^ (lane >> 4);
      GLDS(Wt + (size_t)c * K + kb + gs * 8, &Bs[buf][half][idx * 512]);
    }
  };

  stage(0, 0);
  __syncthreads();

#pragma unroll 1
  for (int t = 0; t < NI; ++t) {
    int buf = t & 1;
    if (t + 1 < NI) stage(t + 1, buf ^ 1);

    bf16x8 ah[2], al[2];
#pragma unroll
    for (int m = 0; m < 2; ++m) {
      int rt = wr * 32 + m * 16 + rlo;
      int p0 = (khi * 2) ^ (rlo & 7), p1 = (khi * 2 + 1) ^ (rlo & 7);
      f32x4 v0 = *reinterpret_cast<const f32x4*>(&As[buf][rt * 32 + p0 * 4]);
      f32x4 v1 = *reinterpret_cast<const f32x4*>(&As[buf][rt * 32 + p1 * 4]);
      float f[8] = {v0.x, v0.y, v0.z, v0.w, v1.x, v1.y, v1.z, v1.w};
#pragma unroll
      for (int i = 0; i < 8; ++i) {
        __bf16 hv = (__bf16)f[i];
        ah[m][i] = hv;
        al[m][i] = (__bf16)(f[i] - (float)hv);
      }
    }
    short8 bh[4], bl[4];
#pragma unroll
    for (int n = 0; n < 4; ++n) {
      int c = wc * 64 + n * 16 + rlo;
      int pos = khi ^ (rlo >> 2);
      bh[n] = *reinterpret_cast<const short8*>(&Bs[buf][0][c * 32 + pos * 8]);
      bl[n] = *reinterpret_cast<const short8*>(&Bs[buf][1][c * 32 + pos * 8]);
    }
#pragma unroll
    for (int m = 0; m < 2; ++m)
#pragma unroll
      for (int n = 0; n < 4; ++n)
        acc[m][n] = __builtin_amdgcn_mfma_f32_16x16x32_bf16(
            ah[m], __builtin_bit_cast(bf16x8, bh[n]), acc[m][n], 0, 0, 0);
#pragma unroll
    for (int m = 0; m < 2; ++m)
#pragma unroll
      for (int n = 0; n < 4; ++n)
        acc[m][n] = __builtin_amdgcn_mfma_f32_16x16x32_bf16(
            al[m], __builtin_bit_cast(bf16x8, bh[n]), acc[m][n], 0, 0, 0);
#pragma unroll
    for (int m = 0; m < 2; ++m)
#pragma unroll
      for (int n = 0; n < 4; ++n)
        acc[m][n] = __builtin_amdgcn_mfma_f32_16x16x32_bf16(
            ah[m], __builtin_bit_cast(bf16x8, bl[n]), acc[m][n], 0, 0, 0);
    __syncthreads();
  }

  // C/D: col = lane&15, row = (lane>>4)*4 + reg; store bf16 (RNE)
#pragma unroll
  for (int m = 0; m < 2; ++m)
#pragma unroll
    for (int j = 0; j < 4; ++j) {
      int row = row0 + m * 16 + khi * 4 + j;
      if (row < M) {
#pragma unroll
        for (int n = 0; n < 4; ++n) {
          __bf16 q = (__bf16)acc[m][n][j];
          Y[(size_t)row * N + wc * 64 + n * 16 + rlo] = __builtin_bit_cast(unsigned short, q);
        }
      }
    }
}

// ---------------- fused: gemm1 (blocks [0,ngemm)) ∥ bin_scatter (rest) ----------------
// Record u64: src:16 | dest_lo:8 | f16(ew):16.
__global__ void __launch_bounds__(512, 4) fused_gemm1_scatter_kernel(
    const float* __restrict__ X, const unsigned short* __restrict__ Bth,
    const unsigned short* __restrict__ Btl, unsigned short* __restrict__ Y, int M,
    int ngemm, const int* __restrict__ ei, const float* __restrict__ ew,
    unsigned int* __restrict__ gclaim, unsigned long long* __restrict__ binned, int nE) {
  if ((int)blockIdx.x < ngemm) {
    gemm_body<IN_C, HID_C, 4, 2>(X, Bth, Btl, Y, M, blockIdx.x);
    return;
  }
  __shared__ unsigned int h[NBUCK];
  __shared__ unsigned int cur[NBUCK];
  int t = threadIdx.x;
  if (t < NBUCK) h[t] = 0;
  __syncthreads();
  int base = ((int)blockIdx.x - ngemm) * 4096;
  int r[8]; unsigned int c[8]; unsigned short wb[8];
#pragma unroll
  for (int i = 0; i < 8; ++i) {
    int e = base + i * 512 + t;
    if (e < nE) {
      r[i] = ei[e];
      c[i] = (unsigned int)ei[nE + e];
      wb[i] = f16bits(ew[e]);
      atomicAdd(&h[c[i] >> 8], 1u);
    } else {
      c[i] = 0xFFFFFFFFu;
    }
  }
  __syncthreads();
  if (t < NBUCK) cur[t] = h[t] ? atomicAdd(&gclaim[t], h[t]) : 0u;
  __syncthreads();
#pragma unroll
  for (int i = 0; i < 8; ++i) {
    if (c[i] != 0xFFFFFFFFu) {
      unsigned int pos = atomicAdd(&cur[c[i] >> 8], 1u);
      unsigned long long rec = (unsigned long long)((unsigned int)r[i] & 0xFFFFu)
                             | ((unsigned long long)(c[i] & 0xFFu) << 16)
                             | ((unsigned long long)wb[i] << 32);
      binned[pos] = rec;
    }
  }
}

// ---------------- bucket_build: deg + CSR build, merged (dinv-fold: no norm here) ------
// Per bucket: LDS hist (count + fixed-point weight sum) -> dinv/offs/cnts -> CSR image
// (record u32: src:16 | f16(ew):16 — raw weight; dinv factors applied in agg) -> coalesced
// write. Self-loop: record src=g, w=1.0 (contribution dinv[g]^2 * feat[g] after agg folds).
// No cross-bucket dependency -> single kernel, binned read twice but L2-warm within block.

__global__ void __launch_bounds__(256) bucket_build_kernel(
    const unsigned long long* __restrict__ binned, const unsigned int* __restrict__ gclaim,
    float* __restrict__ dinv, int* __restrict__ offs, unsigned short* __restrict__ cnts,
    unsigned int* __restrict__ edges) {
  int b = blockIdx.x, t = threadIdx.x;
  int base = b * BCAP;
  int cnt = (int)gclaim[b] - base;
  int nb = min(256, NNODES - b * 256);
  int csrbase = b * BREG;
  __shared__ unsigned int ec[256], wf[256], cur[256];
  __shared__ int sc[256];
  __shared__ unsigned int image[BREG];
  ec[t] = 0; wf[t] = 0;
  __syncthreads();
  // pass 1: per-node edge count + fixed-point weight sum (deterministic)
  for (int i = t; i < cnt; i += 256) {
    unsigned long long rec = binned[base + i];
    int dlo = (int)((rec >> 16) & 255ULL);
    atomicAdd(&ec[dlo], 1u);
    float w = f16val((unsigned short)(rec >> 32));
    atomicAdd(&wf[dlo], (unsigned int)(w * 1048576.0f + 0.5f));   // 2^20 fixed-point
  }
  __syncthreads();
  int cn = (t < nb) ? (int)ec[t] + 1 : 0;   // + self-loop slot
  sc[t] = cn;
  __syncthreads();
  for (int off = 1; off < 256; off <<= 1) {
    int u = (t >= off) ? sc[t - off] : 0;
    __syncthreads();
    sc[t] += u;
    __syncthreads();
  }
  if (t < nb) {
    float deg = (float)wf[t] * (1.0f / 1048576.0f) + 1.0f;   // + self-loop w=1
    int g = b * 256 + t;
    float di = rsqrtf(deg);
    dinv[g] = di;
    int loc = sc[t] - cn;                   // local offset within bucket region
    offs[g] = csrbase + loc;
    cnts[g] = (unsigned short)ec[t];
    cur[t] = (unsigned int)(loc + 1);
    image[loc] = (unsigned int)g | (0x3C00u << 16);   // self-loop, w = f16(1.0)
  }
  __syncthreads();
  // pass 2: place raw-weight records (binned slice is L2-warm from pass 1)
  for (int i = t; i < cnt; i += 256) {
    unsigned long long rec = binned[base + i];
    int src = (int)(rec & 0xFFFFULL);
    int dlo = (int)((rec >> 16) & 255ULL);
    unsigned int wb = (unsigned int)((rec >> 32) & 0xFFFFULL);
    unsigned int pos = atomicAdd(&cur[dlo], 1u);
    image[pos] = (unsigned int)src | (wb << 16);
  }
  __syncthreads();
  int total = cnt + nb;
  for (int j = t; j < total; j += 256) edges[csrbase + j] = image[j];
}

// ---------------- bf16-A MFMA GEMM (layer 2): A already bf16 -> 2 MFMA terms ----------------
template <int K, int N, int WR, int WC>
__global__ void __launch_bounds__(WR * WC * 64, 4) gemm_bf16a_kernel(
    const unsigned short* __restrict__ X, const unsigned short* __restrict__ Bth,
    const unsigned short* __restrict__ Btl, unsigned short* __restrict__ Y, int M) {
  constexpr int NW = WR * WC;
  constexpr int BM = WR * 32;
  constexpr int NI = K / 32;
  constexpr int ASLOTS = (BM / 16) / NW;
  constexpr int BSLOTS = (N / 8) / NW;

  __shared__ unsigned short As[2][BM * 32];
  __shared__ unsigned short Bs[2][2][N * 32];

  int tid = threadIdx.x;
  int lane = tid & 63, wid = tid >> 6;
  int wr = wid / WC, wc = wid % WC;
  int row0blk = blockIdx.x * BM;
  int row0 = row0blk + wr * 32;
  int rlo = lane & 15;
  int khi = lane >> 4;

  f32x4 acc[2][4] = {};

  auto stage = [&](int t, int buf) {
    int kb = t * 32;
#pragma unroll
    for (int i = 0; i < ASLOTS; ++i) {
      int slot = wid * ASLOTS + i;
      int rt = slot * 16 + (lane >> 2);
      int gr = row0blk + rt; gr = gr < M ? gr : M - 1;
      int gs = (lane & 3) ^ ((lane >> 3) & 3);
      GLDS(X + (size_t)gr * K + kb + gs * 8, &As[buf][slot * 512]);
    }
#pragma unroll
    for (int i = 0; i < BSLOTS; ++i) {
      int slot = wid * BSLOTS + i;
      int half = slot / (N / 16);
      int idx = slot % (N / 16);
      const unsigned short* Wt = half ? Btl : Bth;
      int c = idx * 16 + (lane >> 2);
      int gs = (lane & 3) ^ (lane >> 4);
      GLDS(Wt + (size_t)c * K + kb + gs * 8, &Bs[buf][half][idx * 512]);
    }
  };

  stage(0, 0);
  __syncthreads();

#pragma unroll 1
  for (int t = 0; t < NI; ++t) {
    int buf = t & 1;
    if (t + 1 < NI) stage(t + 1, buf ^ 1);

    short8 ah[2];
#pragma unroll
    for (int m = 0; m < 2; ++m) {
      int rt = wr * 32 + m * 16 + rlo;
      int g = khi ^ ((rt >> 1) & 3);
      ah[m] = *reinterpret_cast<const short8*>(&As[buf][rt * 32 + g * 8]);
    }
    short8 bh[4], bl[4];
#pragma unroll
    for (int n = 0; n < 4; ++n) {
      int c = wc * 64 + n * 16 + rlo;
      int pos = khi ^ (rlo >> 2);
      bh[n] = *reinterpret_cast<const short8*>(&Bs[buf][0][c * 32 + pos * 8]);
      bl[n] = *reinterpret_cast<const short8*>(&Bs[buf][1][c * 32 + pos * 8]);
    }
#pragma unroll
    for (int m = 0; m < 2; ++m)
#pragma unroll
      for (int n = 0; n < 4; ++n)
        acc[m][n] = __builtin_amdgcn_mfma_f32_16x16x32_bf16(
            __builtin_bit_cast(bf16x8, ah[m]), __builtin_bit_cast(bf16x8, bh[n]),
            acc[m][n], 0, 0, 0);
#pragma unroll
    for (int m = 0; m < 2; ++m)
#pragma unroll
      for (int n = 0; n < 4; ++n)
        acc[m][n] = __builtin_amdgcn_mfma_f32_16x16x32_bf16(
            __builtin_bit_cast(bf16x8, ah[m]), __builtin_bit_cast(bf16x8, bl[n]),
            acc[m][n], 0, 0, 0);
    __syncthreads();
  }

#pragma unroll
  for (int m = 0; m < 2; ++m)
#pragma unroll
    for (int j = 0; j < 4; ++j) {
      int row = row0 + m * 16 + khi * 4 + j;
      if (row < M) {
#pragma unroll
        for (int n = 0; n < 4; ++n) {
          __bf16 q = (__bf16)acc[m][n][j];
          Y[(size_t)row * N + wc * 64 + n * 16 + rlo] = __builtin_bit_cast(unsigned short, q);
        }
      }
    }
}

// ---------------- CSR aggregation over bf16 features (dinv-folded) ----------------
// out[d] = dinv[d] * sum_e ( f16w(e) * dinv[src] * feat[src] ) + bias  (then relu opt.)
// Record u32: src:16 | f16(ew):16. dinv is 200KB, L2-resident; 16-lane broadcast loads.
template <int F, bool RELU, bool OUTBF>
__global__ void __launch_bounds__(256) agg_kernel(const unsigned short* __restrict__ feat,
                                                  const int* __restrict__ offs,
                                                  const unsigned short* __restrict__ cnts,
                                                  const unsigned int* __restrict__ edges,
                                                  const float* __restrict__ dinv,
                                                  const float* __restrict__ bias,
                                                  void* __restrict__ outv, int n) {
  constexpr int LPN = F / 8;
  constexpr int NPW = 64 / LPN;
  constexpr int NPB = 4 * NPW;
  int wid = threadIdx.x >> 6;
  int lane = threadIdx.x & 63;
  int node = blockIdx.x * NPB + wid * NPW + lane / LPN;
  int lf = (lane % LPN) * 8;
  if (node >= n) return;
  int e0 = offs[node];
  int e1 = e0 + 1 + (int)cnts[node];

  float acc[8] = {};

  auto fmaEdge = [&](unsigned int q) {
    int row = (int)(q & 0xFFFFu);
    float w = f16val((unsigned short)(q >> 16)) * dinv[row];
    short8 v = *reinterpret_cast<const short8*>(&feat[(size_t)row * F + lf]);
#pragma unroll
    for (int j = 0; j < 8; ++j)
      acc[j] = fmaf(w, bf2f((unsigned short)v[j]), acc[j]);
  };

  int e = e0;
  for (; e + 4 <= e1; e += 4) {
    unsigned int q0 = edges[e], q1 = edges[e + 1], q2 = edges[e + 2], q3 = edges[e + 3];
    fmaEdge(q0); fmaEdge(q1); fmaEdge(q2); fmaEdge(q3);
  }
  for (; e < e1; ++e) fmaEdge(edges[e]);

  float dd = dinv[node];
#pragma unroll
  for (int j = 0; j < 8; ++j) {
    acc[j] = fmaf(acc[j], dd, bias[lf + j]);
    if (RELU) acc[j] = fmaxf(acc[j], 0.f);
  }
  if constexpr (OUTBF) {
    short8 o;
#pragma unroll
    for (int j = 0; j < 8; ++j) {
      __bf16 q = (__bf16)acc[j];
      o[j] = (short)__builtin_bit_cast(unsigned short, q);
    }
    *reinterpret_cast<short8*>((unsigned short*)outv + (size_t)node * F + lf) = o;
  } else {
    float* out = (float*)outv;
    float4 o0 = make_float4(acc[0], acc[1], acc[2], acc[3]);
    float4 o1 = make_float4(acc[4], acc[5], acc[6], acc[7]);
    *reinterpret_cast<float4*>(&out[(size_t)node * F + lf]) = o0;
    *reinterpret_cast<float4*>(&out[(size_t)node * F + lf + 4]) = o1;
  }
}

// ---------------- launch ----------------

extern "C" void kernel_launch(void* const* d_in, const int* in_sizes, int n_in,
                              void* d_out, int out_size, void* d_ws, size_t ws_size,
                              hipStream_t stream) {
  const float* x  = (const float*)d_in[0];
  const int*   ei = (const int*)d_in[1];     // [2, E] int
  const float* ew = (const float*)d_in[2];
  const float* W1 = (const float*)d_in[3];
  const float* b1 = (const float*)d_in[4];
  const float* W2 = (const float*)d_in[5];
  const float* b2 = (const float*)d_in[6];
  float* out = (float*)d_out;

  const int N = NNODES, E = NEDGES;

  char* p = (char*)d_ws;
  auto alloc = [&](size_t bytes) { char* r = p; p += (bytes + 255) & ~(size_t)255; return r; };
  unsigned int* gclaim = (unsigned int*)alloc(256 * 4);
  float* dinv   = (float*)alloc((size_t)N * 4);
  int*   offs   = (int*)  alloc((size_t)N * 4);
  unsigned short* cnts = (unsigned short*)alloc((size_t)N * 2);
  unsigned long long* binned = (unsigned long long*)alloc((size_t)NBUCK * BCAP * 8);
  unsigned int* edges  = (unsigned int*)alloc((size_t)NBUCK * BREG * 4);
  unsigned short* xw = (unsigned short*)alloc((size_t)N * HID_C * 2); // bf16 pre-agg / h2
  unsigned short* h  = (unsigned short*)alloc((size_t)N * HID_C * 2); // bf16 layer-1 out
  unsigned short* W1th = (unsigned short*)alloc((size_t)IN_C * HID_C * 2);
  unsigned short* W1tl = (unsigned short*)alloc((size_t)IN_C * HID_C * 2);
  unsigned short* W2th = (unsigned short*)alloc((size_t)HID_C * OUT_C * 2);
  unsigned short* W2tl = (unsigned short*)alloc((size_t)HID_C * OUT_C * 2);

  // prep0: seed gclaim (bucket cursors) + wsplit W1,W2
  const int PREP0 = 256 + IN_C * HID_C + HID_C * OUT_C;
  prep0_kernel<<<(PREP0 + 255) / 256, 256, 0, stream>>>(
      gclaim, W1, W1th, W1tl, W2, W2th, W2tl);

  // fused: gemm1 (391 blocks, xw = bf16(x @ W1)) ∥ bin_scatter (196 blocks)
  const int NGEMM = (N + 127) / 128;
  const int NSCAT = (E + 4095) / 4096;
  fused_gemm1_scatter_kernel<<<NGEMM + NSCAT, 512, 0, stream>>>(
      x, W1th, W1tl, xw, N, NGEMM, ei, ew, gclaim, binned, E);

  // merged deg + CSR build (dinv-fold removed the cross-bucket dependency)
  bucket_build_kernel<<<NBUCK, 256, 0, stream>>>(binned, gclaim, dinv, offs, cnts, edges);

  // layer 1 agg: h = bf16(relu(dinv*agg(xw) + b1))
  agg_kernel<HID_C, true, true><<<(N + 15) / 16, 256, 0, stream>>>(
      xw, offs, cnts, edges, dinv, b1, h, N);

  // layer 2: h2 = bf16(h @ W2)  [bf16-A GEMM, BM=256, N=64, 8 waves]
  gemm_bf16a_kernel<HID_C, OUT_C, 8, 1><<<(N + 255) / 256, 512, 0, stream>>>(h, W2th, W2tl, xw, N);
  agg_kernel<OUT_C, false, false><<<(N + 31) / 32, 256, 0, stream>>>(
      xw, offs, cnts, edges, dinv, b2, out, N);
}